// Round 10
// baseline (274.687 us; speedup 1.0000x reference)
//
#include <hip/hip_runtime.h>
#include <math.h>

namespace {

constexpr int cB = 32, cL = 128, cG = 64, cD = 256;
constexpr int cHD = 128, cH = 256;
constexpr int cN = 8, cK = 4;
constexpr int cNI = 128, cRH = 512;
constexpr int cE = 2048;
constexpr float cEPS = 1e-5f;

typedef __bf16 bf16x8 __attribute__((ext_vector_type(8)));
typedef float f32x4 __attribute__((ext_vector_type(4)));

__device__ __forceinline__ f32x4 mfma16(bf16x8 a, bf16x8 b, f32x4 c) {
    return __builtin_amdgcn_mfma_f32_16x16x32_bf16(a, b, c, 0, 0, 0);
}

__device__ __forceinline__ float bf2f(unsigned short u) {
    unsigned int x = ((unsigned int)u) << 16;
    return __uint_as_float(x);
}
__device__ __forceinline__ unsigned short f2bf(float f) {
    unsigned int x = __float_as_uint(f);
    unsigned int r = (x + 0x7fffu + ((x >> 16) & 1u)) >> 16;  // RNE
    return (unsigned short)r;
}
__device__ __forceinline__ float frcp(float x) { return __builtin_amdgcn_rcpf(x); }
__device__ __forceinline__ float fsig(float x) { return frcp(1.f + __expf(-x)); }
__device__ __forceinline__ float ftanh(float x) { return 1.f - 2.f * frcp(__expf(2.f * x) + 1.f); }
__device__ __forceinline__ float nls(float x) {
    return (x >= 0.f) ? log1pf(expf(-x)) : (log1pf(expf(x)) - x);
}
__device__ __forceinline__ bf16x8 cvt8(const float* __restrict__ p) {
    float4 a = *(const float4*)p, b = *(const float4*)(p + 4);
    bf16x8 v;
    v[0] = (__bf16)a.x; v[1] = (__bf16)a.y; v[2] = (__bf16)a.z; v[3] = (__bf16)a.w;
    v[4] = (__bf16)b.x; v[5] = (__bf16)b.y; v[6] = (__bf16)b.z; v[7] = (__bf16)b.w;
    return v;
}

// lgkm-only barrier: LDS ping-pong needs lgkmcnt ordering, NOT a vmcnt(0) drain.
__device__ __forceinline__ void bar_lgkm() {
    asm volatile("s_waitcnt lgkmcnt(0)\n\ts_barrier" ::: "memory");
}

// ---------------------------------------------------------------------------
// 1) token embedding + scatter_sum. Preloaded (tok,grp) + 4x unrolled loads.
__global__ __launch_bounds__(256) void k_embed(
    const int* __restrict__ seq, const int* __restrict__ p2g,
    const float* __restrict__ emb, float* __restrict__ x_seq) {
    __shared__ float xl[cG * cD];
    __shared__ int toks[cL], grps[cL];
    int b = blockIdx.x, t = threadIdx.x;
    if (t < 128) toks[t] = seq[b * cL + t];
    else grps[t - 128] = p2g[b * cL + (t - 128)];
    for (int g = 0; g < cG; ++g) xl[g * cD + t] = 0.f;
    __syncthreads();
    for (int l = 0; l < cL; l += 4) {
        float v0 = emb[(size_t)toks[l + 0] * cD + t];
        float v1 = emb[(size_t)toks[l + 1] * cD + t];
        float v2 = emb[(size_t)toks[l + 2] * cD + t];
        float v3 = emb[(size_t)toks[l + 3] * cD + t];
        xl[grps[l + 0] * cD + t] += v0;
        xl[grps[l + 1] * cD + t] += v1;
        xl[grps[l + 2] * cD + t] += v2;
        xl[grps[l + 3] * cD + t] += v3;
    }
    for (int g = 0; g < cG; ++g)
        x_seq[(g * cB + b) * cD + t] = xl[g * cD + t];
}

// ---------------------------------------------------------------------------
// 2) LSTM input GEMM via MFMA (verified).
__global__ __launch_bounds__(512) void k_gemm_in(
    const float* __restrict__ x_seq,
    const float* __restrict__ wih_f, const float* __restrict__ wih_b,
    const float* __restrict__ bih_f, const float* __restrict__ bhh_f,
    const float* __restrict__ bih_b, const float* __restrict__ bhh_b,
    float* __restrict__ pre) {
    int ns = blockIdx.x, g = blockIdx.y;
    int t = threadIdx.x;
    int w = t >> 6, l = t & 63, lc = l & 15, lk = l >> 4;
    int gn = ns * 128 + w * 16 + lc;
    const float* wrow = (gn < 512) ? (wih_f + (size_t)gn * cD)
                                   : (wih_b + (size_t)(gn - 512) * cD);
    const float* xb0 = x_seq + ((size_t)g * 32 + lc) * cD;
    const float* xb1 = x_seq + ((size_t)g * 32 + 16 + lc) * cD;
    f32x4 acc0 = {0.f, 0.f, 0.f, 0.f}, acc1 = {0.f, 0.f, 0.f, 0.f};
#pragma unroll
    for (int kf = 0; kf < 8; ++kf) {
        int ko = kf * 32 + lk * 8;
        bf16x8 a = cvt8(wrow + ko);
        bf16x8 b0 = cvt8(xb0 + ko);
        bf16x8 b1 = cvt8(xb1 + ko);
        acc0 = mfma16(a, b0, acc0);
        acc1 = mfma16(a, b1, acc1);
    }
    int nb = ns * 128 + w * 16 + lk * 4;
    float4 bv;
    if (nb < 512) {
        float4 u = *(const float4*)(bih_f + nb);
        float4 v = *(const float4*)(bhh_f + nb);
        bv = make_float4(u.x + v.x, u.y + v.y, u.z + v.z, u.w + v.w);
    } else {
        float4 u = *(const float4*)(bih_b + nb - 512);
        float4 v = *(const float4*)(bhh_b + nb - 512);
        bv = make_float4(u.x + v.x, u.y + v.y, u.z + v.z, u.w + v.w);
    }
    size_t base = ((size_t)g * 256 + (nb >> 2)) * 32;
    *(float4*)(pre + (base + lc) * 4) =
        make_float4(acc0[0] + bv.x, acc0[1] + bv.y, acc0[2] + bv.z, acc0[3] + bv.w);
    *(float4*)(pre + (base + 16 + lc) * 4) =
        make_float4(acc1[0] + bv.x, acc1[1] + bv.y, acc1[2] + bv.z, acc1[3] + bv.w);
}

// ---------------------------------------------------------------------------
// 3) MFMA LSTM v6: DIR-INTERLEAVED, launch_bounds(512,1) so the ~230-VGPR
//    state (both dirs' weights + 4 acc sets) fits WITHOUT spilling.
//    2 blocks = bhalf; 512 thr = 8 waves (2/SIMD on 2 CUs).
__device__ __forceinline__ void step2(
    f32x4 (&a0)[4], f32x4 (&a1)[4], float (&c0)[4], float (&c1)[4],
    const bf16x8 (&wf0)[4][4], const bf16x8 (&wf1)[4][4],
    const unsigned short* __restrict__ hr0, unsigned short* __restrict__ hw0,
    const unsigned short* __restrict__ hr1, unsigned short* __restrict__ hw1,
    const int (&rdo)[4], int wro,
    const float* __restrict__ preb0, const float* __restrict__ preb1,
    int gp0, int gp1, bool dopre,
    unsigned short* __restrict__ hob0, unsigned short* __restrict__ hob1,
    int g0, int g1) {
    bf16x8 hf0[4], hf1[4];
#pragma unroll
    for (int kf = 0; kf < 4; ++kf) {
        hf0[kf] = *(const bf16x8*)((const char*)hr0 + rdo[kf]);
        hf1[kf] = *(const bf16x8*)((const char*)hr1 + rdo[kf]);
    }
#pragma unroll
    for (int kf = 0; kf < 4; ++kf) {
#pragma unroll
        for (int q = 0; q < 4; ++q) {
            a0[q] = mfma16(wf0[q][kf], hf0[kf], a0[q]);
            a1[q] = mfma16(wf1[q][kf], hf1[kf], a1[q]);
        }
    }
    float hv0[4], hv1[4];
#pragma unroll
    for (int r = 0; r < 4; ++r) {
        float ig0 = fsig(a0[0][r]), ig1 = fsig(a1[0][r]);
        float fg0 = fsig(a0[1][r]), fg1 = fsig(a1[1][r]);
        float gg0 = ftanh(a0[2][r]), gg1 = ftanh(a1[2][r]);
        float og0 = fsig(a0[3][r]), og1 = fsig(a1[3][r]);
        float cv0 = fg0 * c0[r] + ig0 * gg0;
        float cv1 = fg1 * c1[r] + ig1 * gg1;
        c0[r] = cv0;
        c1[r] = cv1;
        hv0[r] = og0 * ftanh(cv0);
        hv1[r] = og1 * ftanh(cv1);
    }
    if (dopre) {
#pragma unroll
        for (int q = 0; q < 4; ++q) {
            a0[q] = *(const f32x4*)(preb0 + (size_t)gp0 * 32768 + q * 4096);
            a1[q] = *(const f32x4*)(preb1 + (size_t)gp1 * 32768 + q * 4096);
        }
    }
    unsigned int p00 = (unsigned int)f2bf(hv0[0]) | ((unsigned int)f2bf(hv0[1]) << 16);
    unsigned int p01 = (unsigned int)f2bf(hv0[2]) | ((unsigned int)f2bf(hv0[3]) << 16);
    unsigned int p10 = (unsigned int)f2bf(hv1[0]) | ((unsigned int)f2bf(hv1[1]) << 16);
    unsigned int p11 = (unsigned int)f2bf(hv1[2]) | ((unsigned int)f2bf(hv1[3]) << 16);
    *(uint2*)((char*)hw0 + wro) = make_uint2(p00, p01);
    *(uint2*)((char*)hw1 + wro) = make_uint2(p10, p11);
    *(uint2*)(hob0 + (size_t)g0 * 8192) = make_uint2(p00, p01);
    *(uint2*)(hob1 + (size_t)g1 * 8192) = make_uint2(p10, p11);
    bar_lgkm();
}

__global__ __launch_bounds__(512, 1) void k_lstm_m(
    const float* __restrict__ pre,
    const float* __restrict__ whh_f, const float* __restrict__ whh_b,
    unsigned short* __restrict__ h_out) {
    __shared__ __align__(16) unsigned short hl0[2][2048];
    __shared__ __align__(16) unsigned short hl1[2][2048];
    int t = threadIdx.x;
    int w = t >> 6, l = t & 63, lc = l & 15, lk = l >> 4;
    int bg = blockIdx.x * 16;
    // stationary A-fragments for BOTH dirs
    bf16x8 wf0[4][4], wf1[4][4];
#pragma unroll
    for (int q = 0; q < 4; ++q) {
        int n = q * 128 + w * 16 + lc;
#pragma unroll
        for (int kf = 0; kf < 4; ++kf) {
            wf0[q][kf] = cvt8(whh_f + (size_t)n * 128 + kf * 32 + lk * 8);
            wf1[q][kf] = cvt8(whh_b + (size_t)n * 128 + kf * 32 + lk * 8);
        }
    }
    *(uint2*)&hl0[1][t * 4] = make_uint2(0u, 0u);
    *(uint2*)&hl1[1][t * 4] = make_uint2(0u, 0u);
    const float* preb0 = pre + ((size_t)(w * 4 + lk) * 32 + (bg + lc)) * 4;
    const float* preb1 = pre + ((size_t)(128 + w * 4 + lk) * 32 + (bg + lc)) * 4;
    unsigned short* hob0 = h_out + ((size_t)(bg + lc) * 128 + w * 16 + lk * 4);
    unsigned short* hob1 = h_out + ((size_t)(32 + bg + lc) * 128 + w * 16 + lk * 4);
    int rdo[4];
#pragma unroll
    for (int kf = 0; kf < 4; ++kf)
        rdo[kf] = (lc * 256 + kf * 64 + lk * 16) ^ (lc << 4);
    int wro = (lc * 256 + w * 32 + lk * 8) ^ (lc << 4);
    f32x4 aA0[4], aB0[4], aA1[4], aB1[4];
    float c0[4] = {0.f, 0.f, 0.f, 0.f}, c1[4] = {0.f, 0.f, 0.f, 0.f};
#pragma unroll
    for (int q = 0; q < 4; ++q) {
        aA0[q] = *(const f32x4*)(preb0 + (size_t)0 * 32768 + q * 4096);
        aA1[q] = *(const f32x4*)(preb1 + (size_t)63 * 32768 + q * 4096);
        aB0[q] = *(const f32x4*)(preb0 + (size_t)1 * 32768 + q * 4096);
        aB1[q] = *(const f32x4*)(preb1 + (size_t)62 * 32768 + q * 4096);
    }
    bar_lgkm();  // zero-init visible
    for (int s = 0; s < 64; s += 2) {
        // logical step s: dir0 g=s, dir1 g=63-s; prefetch s+2 / 61-s
        step2(aA0, aA1, c0, c1, wf0, wf1,
              hl0[1], hl0[0], hl1[1], hl1[0], rdo, wro,
              preb0, preb1, s + 2, 61 - s, s < 62, hob0, hob1, s, 63 - s);
        // logical step s+1: dir0 g=s+1, dir1 g=62-s; prefetch s+3 / 60-s
        step2(aB0, aB1, c0, c1, wf0, wf1,
              hl0[0], hl0[1], hl1[0], hl1[1], rdo, wro,
              preb0, preb1, s + 3, 60 - s, s < 61, hob0, hob1, s + 1, 62 - s);
    }
}

// ---------------------------------------------------------------------------
// 4) gather(+sum over K) -> transposed hsumT[c][n]. 256 blocks = node.
__global__ __launch_bounds__(256) void k_gather(
    const int* __restrict__ idx, const int* __restrict__ p2g,
    const unsigned short* __restrict__ h_out, float* __restrict__ hsumT) {
    int bn = blockIdx.x;
    int b = bn >> 3;
    int t = threadIdx.x;
    int dirq = t >> 7, hh = t & 127;
    int l0 = idx[bn * cK + 0], l1 = idx[bn * cK + 1];
    int l2 = idx[bn * cK + 2], l3 = idx[bn * cK + 3];
    int g0 = p2g[b * cL + l0], g1 = p2g[b * cL + l1];
    int g2 = p2g[b * cL + l2], g3 = p2g[b * cL + l3];
    size_t ro = (size_t)(dirq * 32 + b) * 128 + hh;
    float a = bf2f(h_out[(size_t)g0 * 8192 + ro]) + bf2f(h_out[(size_t)g1 * 8192 + ro]) +
              bf2f(h_out[(size_t)g2 * 8192 + ro]) + bf2f(h_out[(size_t)g3 * 8192 + ro]);
    hsumT[(size_t)t * 256 + bn] = a;
}

// ---------------------------------------------------------------------------
// 5) fused projection + BatchNorm (verified).
__global__ __launch_bounds__(256) void k_proj_bn(
    const float* __restrict__ hsumT,
    const float* __restrict__ w_src, const float* __restrict__ b_src,
    const float* __restrict__ w_dst, const float* __restrict__ b_dst,
    const float* __restrict__ g_src, const float* __restrict__ bb_src,
    const float* __restrict__ g_dst, const float* __restrict__ bb_dst,
    float* __restrict__ hd_bn, float* __restrict__ tl_bn) {
    int which = blockIdx.x, c = blockIdx.y, t = threadIdx.x;
    __shared__ float ws[256];
    __shared__ float ssum[256], ssq[256];
    ws[t] = (which ? w_dst : w_src)[(size_t)c * cH + t];
    __syncthreads();
    float acc = (which ? b_dst : b_src)[c];
#pragma unroll 8
    for (int k = 0; k < cH; ++k)
        acc += ws[k] * hsumT[(size_t)k * 256 + t];
    ssum[t] = acc;
    ssq[t] = acc * acc;
    __syncthreads();
    for (int o = 128; o > 0; o >>= 1) {
        if (t < o) { ssum[t] += ssum[t + o]; ssq[t] += ssq[t + o]; }
        __syncthreads();
    }
    float mean = ssum[0] * (1.f / 256.f);
    float var = ssq[0] * (1.f / 256.f) - mean * mean;
    float gam = which ? g_dst[c] : g_src[c];
    float bet = which ? bb_dst[c] : bb_src[c];
    float scale = gam * rsqrtf(var + cEPS);
    (which ? tl_bn : hd_bn)[(size_t)t * cNI + c] = (acc - mean) * scale + bet;
}

// ---------------------------------------------------------------------------
// 6) MFMA NTL-A + fused lin (verified, unchanged).
__global__ __launch_bounds__(256, 2) void k_ntl_A(
    const float* __restrict__ hd_bn, const float* __restrict__ tl_bn,
    const float* __restrict__ ntl_w, const float* __restrict__ ntl_v,
    unsigned short* __restrict__ tmp,
    float* __restrict__ lsrc, float* __restrict__ ldst) {
    __shared__ __align__(16) unsigned short wl[128 * 128];
    __shared__ float vsh[256];
    int rh = blockIdx.x, t = threadIdx.x;
    int w = t >> 6, l = t & 63, lc = l & 15, lk = l >> 4;
    vsh[t] = ntl_v[(size_t)rh * 256 + t];
    {
        const float* wbase = ntl_w + (size_t)rh * 16384;
        int k = t >> 1, c0 = (t & 1) * 64;
        int sw = ((k >> 3) & 3) << 4;
#pragma unroll
        for (int u = 0; u < 8; ++u) {
            bf16x8 v = cvt8(wbase + k * 128 + c0 + u * 8);
            *(bf16x8*)((char*)wl + ((k * 256 + (c0 + u * 8) * 2) ^ sw)) = v;
        }
    }
    __syncthreads();
    {
        const float* hr = hd_bn + (size_t)t * cNI;
        const float* tr = tl_bn + (size_t)t * cNI;
        float a1 = 0.f, a2 = 0.f;
#pragma unroll 8
        for (int i = 0; i < cNI; i += 4) {
            float4 h4 = *(const float4*)(hr + i);
            float4 t4 = *(const float4*)(tr + i);
            a1 += h4.x * vsh[i] + h4.y * vsh[i + 1] + h4.z * vsh[i + 2] + h4.w * vsh[i + 3];
            a2 += t4.x * vsh[128 + i] + t4.y * vsh[128 + i + 1] + t4.z * vsh[128 + i + 2] + t4.w * vsh[128 + i + 3];
        }
        lsrc[(size_t)rh * 256 + t] = a1;
        ldst[(size_t)rh * 256 + t] = a2;
    }
    f32x4 acc[4][8] = {};
#pragma unroll
    for (int kf = 0; kf < 4; ++kf) {
        bf16x8 af[4];
#pragma unroll
        for (int mt = 0; mt < 4; ++mt) {
            int m = w * 64 + mt * 16 + lc;
            af[mt] = cvt8(hd_bn + (size_t)m * 128 + kf * 32 + lk * 8);
        }
#pragma unroll
        for (int nt = 0; nt < 8; ++nt) {
            int kb = (kf * 32 + lk * 8) * 256;
            int jb = (nt * 16 + lc) * 2;
            bf16x8 bv = *(const bf16x8*)((char*)wl + ((kb + jb) ^ (lk << 4)));
#pragma unroll
            for (int mt = 0; mt < 4; ++mt) acc[mt][nt] = mfma16(af[mt], bv, acc[mt][nt]);
        }
    }
#pragma unroll
    for (int mt = 0; mt < 4; ++mt) {
#pragma unroll
        for (int nt = 0; nt < 8; ++nt) {
            unsigned int lo = (unsigned int)f2bf(acc[mt][nt][0]) | ((unsigned int)f2bf(acc[mt][nt][1]) << 16);
            unsigned int hi = (unsigned int)f2bf(acc[mt][nt][2]) | ((unsigned int)f2bf(acc[mt][nt][3]) << 16);
            size_t off = (size_t)rh * 32768 + (size_t)((((w * 4 + mt) * 8 + nt) * 64 + l) * 4);
            *(uint2*)(tmp + off) = make_uint2(lo, hi);
        }
    }
}

// ---------------------------------------------------------------------------
// 7) bilinear + linear + bias -> pre2[rh][e], + BN partials (verified).
__global__ __launch_bounds__(64) void k_ntl_B(
    const unsigned short* __restrict__ tmp, const float* __restrict__ tl_bn,
    const float* __restrict__ lsrc, const float* __restrict__ ldst,
    const float* __restrict__ ntl_b, float* __restrict__ pre2,
    float2* __restrict__ part2) {
    int bgid = blockIdx.x;
    int rh = blockIdx.y;
    int t = threadIdx.x;
    int n0 = bgid * 32;
    __shared__ float tm[32][132];
    __shared__ float tl[32][132];
    {
        const uint4* src = (const uint4*)(tmp + (size_t)rh * 32768 +
                                          (size_t)(bgid >> 1) * 8192 + (size_t)(bgid & 1) * 4096);
#pragma unroll
        for (int rep = 0; rep < 8; ++rep) {
            int q = t + rep * 64;
            uint4 uv = src[q];
            unsigned int wds[4] = {uv.x, uv.y, uv.z, uv.w};
            int e0 = q * 8;
#pragma unroll
            for (int ui = 0; ui < 4; ++ui) {
                int e = e0 + ui * 2;
                int mt_l = e >> 11;
                int nt = (e >> 8) & 7;
                int ln = (e >> 2) & 63;
                int r = e & 3;
                int m = mt_l * 16 + (ln >> 4) * 4 + r;
                int j = nt * 16 + (ln & 15);
                tm[m][j] = bf2f((unsigned short)(wds[ui] & 0xffff));
                tm[m + 1][j] = bf2f((unsigned short)(wds[ui] >> 16));
            }
        }
#pragma unroll
        for (int rep = 0; rep < 4; ++rep) {
            int tt = t + rep * 64;
            int r = tt >> 3;
            int c0 = (tt & 7) * 16;
            const float4* fsrc = (const float4*)(tl_bn + (size_t)(n0 + r) * cNI + c0);
            float4 f0 = fsrc[0], f1 = fsrc[1], f2v = fsrc[2], f3 = fsrc[3];
            float* frow = &tl[r][c0];
            frow[0] = f0.x; frow[1] = f0.y; frow[2] = f0.z; frow[3] = f0.w;
            frow[4] = f1.x; frow[5] = f1.y; frow[6] = f1.z; frow[7] = f1.w;
            frow[8] = f2v.x; frow[9] = f2v.y; frow[10] = f2v.z; frow[11] = f2v.w;
            frow[12] = f3.x; frow[13] = f3.y; frow[14] = f3.z; frow[15] = f3.w;
        }
    }
    __syncthreads();
    int b_l = t >> 4, i2 = (t >> 2) & 3, j2 = t & 3;
    const float* ta0 = &tm[b_l * 8 + i2][0];
    const float* ta1 = &tm[b_l * 8 + i2 + 4][0];
    const float* tb0 = &tl[b_l * 8 + j2][0];
    const float* tb1 = &tl[b_l * 8 + j2 + 4][0];
    float s00 = 0.f, s01 = 0.f, s10 = 0.f, s11 = 0.f;
#pragma unroll 4
    for (int k = 0; k < 128; ++k) {
        float a0 = ta0[k], a1 = ta1[k], b0 = tb0[k], b1 = tb1[k];
        s00 += a0 * b0; s01 += a0 * b1; s10 += a1 * b0; s11 += a1 * b1;
    }
    int bglob = bgid * 4 + b_l;
    float nb = ntl_b[rh];
    const float* ls = lsrc + (size_t)rh * 256 + bglob * 8;
    const float* ld = ldst + (size_t)rh * 256 + bglob * 8;
    float* pr = pre2 + (size_t)rh * cE + bgid * 256 + b_l * 64;
    float vs[4];
    vs[0] = s00 + ls[i2] + ld[j2] + nb;
    vs[1] = s01 + ls[i2] + ld[j2 + 4] + nb;
    vs[2] = s10 + ls[i2 + 4] + ld[j2] + nb;
    vs[3] = s11 + ls[i2 + 4] + ld[j2 + 4] + nb;
    pr[i2 * 8 + j2] = vs[0];
    pr[i2 * 8 + j2 + 4] = vs[1];
    pr[(i2 + 4) * 8 + j2] = vs[2];
    pr[(i2 + 4) * 8 + j2 + 4] = vs[3];
    float sm = vs[0] + vs[1] + vs[2] + vs[3];
    float sq = vs[0] * vs[0] + vs[1] * vs[1] + vs[2] * vs[2] + vs[3] * vs[3];
#pragma unroll
    for (int o = 32; o > 0; o >>= 1) {
        sm += __shfl_down(sm, o);
        sq += __shfl_down(sq, o);
    }
    if (t == 0) part2[(size_t)rh * 8 + bgid] = make_float2(sm, sq);
}

// ---------------------------------------------------------------------------
// 8) logit + in-kernel BN2 + fused loss partials (verified).
__global__ __launch_bounds__(256) void k_final(
    const float* __restrict__ pre2, const float2* __restrict__ part2,
    const float* __restrict__ g2, const float* __restrict__ b2,
    const float* __restrict__ ntl_u, const int* __restrict__ mask,
    float* __restrict__ out, float* __restrict__ part) {
    int r = blockIdx.y, et = blockIdx.x;
    int t = threadIdx.x;
    __shared__ float sc[32], sh[32];
    {
        int rh_l = t >> 3, slot = t & 7;
        int rh = r * 32 + rh_l;
        float2 pp = part2[(size_t)rh * 8 + slot];
        float S = pp.x, Q = pp.y;
        S += __shfl_xor(S, 1); Q += __shfl_xor(Q, 1);
        S += __shfl_xor(S, 2); Q += __shfl_xor(Q, 2);
        S += __shfl_xor(S, 4); Q += __shfl_xor(Q, 4);
        if (slot == 0) {
            float mean = S * (1.f / 2048.f);
            float var = Q * (1.f / 2048.f) - mean * mean;
            float scv = g2[rh] * rsqrtf(var + cEPS);
            sc[rh_l] = scv;
            sh[rh_l] = b2[rh] - mean * scv;
        }
    }
    __syncthreads();
    int e = et * 256 + t;
    float a = 0.f;
#pragma unroll
    for (int h = 0; h < 32; ++h) {
        int rh = r * 32 + h;
        float p = pre2[(size_t)rh * cE + e];
        a += ntl_u[rh] * ftanh(fmaf(p, sc[h], sh[h]));
    }
    out[(size_t)e * 16 + r] = a;
    int m = mask[(size_t)e * 16 + r];
    bool mb = (m != 0);
    bool eq = ((a > 0.f) == mb);
    float nll = mb ? nls(a) : -logf(1.f / (1.f + expf(a)) + 1e-5f);
    float corr = eq ? 1.f : 0.f;
    unsigned long long bal = __ballot(eq);
    float em = (bal == ~0ull) ? 1.f : 0.f;
#pragma unroll
    for (int o = 32; o > 0; o >>= 1) {
        nll += __shfl_down(nll, o);
        corr += __shfl_down(corr, o);
    }
    if ((t & 63) == 0) {
        int bg = et * 4 + (t >> 6);
        float* p = part + ((size_t)bg * 16 + r) * 4;
        p[0] = nll; p[1] = corr; p[2] = em;
    }
}

// ---------------------------------------------------------------------------
// 9) final loss reduction
__global__ void k_loss_fin(const float* __restrict__ part, float* __restrict__ out) {
    int t = threadIdx.x;
    float nll = 0.f, corr = 0.f, em = 0.f;
    if (t < 32) {
        em = 1.f;
        for (int r = 0; r < 16; ++r) {
            const float* p = part + ((size_t)t * 16 + r) * 4;
            nll += p[0]; corr += p[1]; em = fminf(em, p[2]);
        }
    }
#pragma unroll
    for (int o = 32; o > 0; o >>= 1) {
        nll += __shfl_down(nll, o);
        corr += __shfl_down(corr, o);
        em += __shfl_down(em, o);
    }
    if (t == 0) {
        out[32768] = nll / 32.f;
        out[32769] = corr / 32768.f;
        out[32770] = em / 32.f;
    }
}

}  // namespace

extern "C" void kernel_launch(void* const* d_in, const int* in_sizes, int n_in,
                              void* d_out, int out_size, void* d_ws, size_t ws_size,
                              hipStream_t stream) {
    (void)in_sizes; (void)n_in; (void)out_size; (void)ws_size;
    const int* seq = (const int*)d_in[0];
    const int* p2g = (const int*)d_in[1];
    const int* idx = (const int*)d_in[2];
    const int* mask = (const int*)d_in[5];
    const float* emb = (const float*)d_in[6];
    const float* wih_f = (const float*)d_in[7];
    const float* whh_f = (const float*)d_in[8];
    const float* bih_f = (const float*)d_in[9];
    const float* bhh_f = (const float*)d_in[10];
    const float* wih_b = (const float*)d_in[11];
    const float* whh_b = (const float*)d_in[12];
    const float* bih_b = (const float*)d_in[13];
    const float* bhh_b = (const float*)d_in[14];
    const float* lsw = (const float*)d_in[15];
    const float* lsb = (const float*)d_in[16];
    const float* ldw = (const float*)d_in[17];
    const float* ldb = (const float*)d_in[18];
    const float* bn_sg = (const float*)d_in[19];
    const float* bn_sb = (const float*)d_in[20];
    const float* bn_dg = (const float*)d_in[21];
    const float* bn_db = (const float*)d_in[22];
    const float* ntlw = (const float*)d_in[23];
    const float* ntlv = (const float*)d_in[24];
    const float* ntlb = (const float*)d_in[25];
    const float* ntlu = (const float*)d_in[26];
    const float* bn2g = (const float*)d_in[27];
    const float* bn2b = (const float*)d_in[28];
    float* out = (float*)d_out;
    char* ws = (char*)d_ws;

    float* x_seq = (float*)(ws + 0);
    float* pre = (float*)(ws + 2097152);
    unsigned short* tmp = (unsigned short*)(ws + 0);
    size_t off = 33554432;
    unsigned short* h_out = (unsigned short*)(ws + off); off += 1048576;
    float* hsumT = (float*)(ws + off); off += 262144;
    float* hd_bn = (float*)(ws + off); off += 131072;
    float* tl_bn = (float*)(ws + off); off += 131072;
    float* lsrc = (float*)(ws + off); off += 524288;
    float* ldst = (float*)(ws + off); off += 524288;
    float* pre2 = (float*)(ws + off); off += 4194304;
    float2* part2 = (float2*)(ws + off); off += 32768;
    float* part = (float*)(ws + off); off += 8192;

    k_embed<<<32, 256, 0, stream>>>(seq, p2g, emb, x_seq);
    k_gemm_in<<<dim3(8, 64), 512, 0, stream>>>(x_seq, wih_f, wih_b, bih_f, bhh_f, bih_b, bhh_b, pre);
    k_lstm_m<<<2, 512, 0, stream>>>(pre, whh_f, whh_b, h_out);
    k_gather<<<256, 256, 0, stream>>>(idx, p2g, h_out, hsumT);
    k_proj_bn<<<dim3(2, 128), 256, 0, stream>>>(hsumT, lsw, lsb, ldw, ldb,
                                                bn_sg, bn_sb, bn_dg, bn_db, hd_bn, tl_bn);
    k_ntl_A<<<512, 256, 0, stream>>>(hd_bn, tl_bn, ntlw, ntlv, tmp, lsrc, ldst);
    k_ntl_B<<<dim3(8, 512), 64, 0, stream>>>(tmp, tl_bn, lsrc, ldst, ntlb, pre2, part2);
    k_final<<<dim3(8, 16), 256, 0, stream>>>(pre2, part2, bn2g, bn2b, ntlu, mask, out, part);
    k_loss_fin<<<1, 64, 0, stream>>>(part, out);
}

// Round 11
// 243.961 us; speedup vs baseline: 1.1259x; 1.1259x over previous
//
#include <hip/hip_runtime.h>
#include <math.h>

namespace {

constexpr int cB = 32, cL = 128, cG = 64, cD = 256;
constexpr int cHD = 128, cH = 256;
constexpr int cN = 8, cK = 4;
constexpr int cNI = 128, cRH = 512;
constexpr int cE = 2048;
constexpr float cEPS = 1e-5f;

typedef __bf16 bf16x8 __attribute__((ext_vector_type(8)));
typedef float f32x4 __attribute__((ext_vector_type(4)));

__device__ __forceinline__ f32x4 mfma16(bf16x8 a, bf16x8 b, f32x4 c) {
    return __builtin_amdgcn_mfma_f32_16x16x32_bf16(a, b, c, 0, 0, 0);
}

__device__ __forceinline__ float bf2f(unsigned short u) {
    unsigned int x = ((unsigned int)u) << 16;
    return __uint_as_float(x);
}
__device__ __forceinline__ unsigned short f2bf(float f) {
    unsigned int x = __float_as_uint(f);
    unsigned int r = (x + 0x7fffu + ((x >> 16) & 1u)) >> 16;  // RNE
    return (unsigned short)r;
}
__device__ __forceinline__ float frcp(float x) { return __builtin_amdgcn_rcpf(x); }
__device__ __forceinline__ float fsig(float x) { return frcp(1.f + __expf(-x)); }
__device__ __forceinline__ float ftanh(float x) { return 1.f - 2.f * frcp(__expf(2.f * x) + 1.f); }
__device__ __forceinline__ float nls(float x) {
    return (x >= 0.f) ? log1pf(expf(-x)) : (log1pf(expf(x)) - x);
}
__device__ __forceinline__ bf16x8 cvt8(const float* __restrict__ p) {
    float4 a = *(const float4*)p, b = *(const float4*)(p + 4);
    bf16x8 v;
    v[0] = (__bf16)a.x; v[1] = (__bf16)a.y; v[2] = (__bf16)a.z; v[3] = (__bf16)a.w;
    v[4] = (__bf16)b.x; v[5] = (__bf16)b.y; v[6] = (__bf16)b.z; v[7] = (__bf16)b.w;
    return v;
}

// lgkm-only barrier: LDS ping-pong needs lgkmcnt ordering, NOT a vmcnt(0) drain.
__device__ __forceinline__ void bar_lgkm() {
    asm volatile("s_waitcnt lgkmcnt(0)\n\ts_barrier" ::: "memory");
}

// ---------------------------------------------------------------------------
// 1) token embedding + scatter_sum. Preloaded (tok,grp) + 4x unrolled loads.
__global__ __launch_bounds__(256) void k_embed(
    const int* __restrict__ seq, const int* __restrict__ p2g,
    const float* __restrict__ emb, float* __restrict__ x_seq) {
    __shared__ float xl[cG * cD];
    __shared__ int toks[cL], grps[cL];
    int b = blockIdx.x, t = threadIdx.x;
    if (t < 128) toks[t] = seq[b * cL + t];
    else grps[t - 128] = p2g[b * cL + (t - 128)];
    for (int g = 0; g < cG; ++g) xl[g * cD + t] = 0.f;
    __syncthreads();
    for (int l = 0; l < cL; l += 4) {
        float v0 = emb[(size_t)toks[l + 0] * cD + t];
        float v1 = emb[(size_t)toks[l + 1] * cD + t];
        float v2 = emb[(size_t)toks[l + 2] * cD + t];
        float v3 = emb[(size_t)toks[l + 3] * cD + t];
        xl[grps[l + 0] * cD + t] += v0;
        xl[grps[l + 1] * cD + t] += v1;
        xl[grps[l + 2] * cD + t] += v2;
        xl[grps[l + 3] * cD + t] += v3;
    }
    for (int g = 0; g < cG; ++g)
        x_seq[(g * cB + b) * cD + t] = xl[g * cD + t];
}

// ---------------------------------------------------------------------------
// 2) LSTM input GEMM via MFMA (verified).
__global__ __launch_bounds__(512) void k_gemm_in(
    const float* __restrict__ x_seq,
    const float* __restrict__ wih_f, const float* __restrict__ wih_b,
    const float* __restrict__ bih_f, const float* __restrict__ bhh_f,
    const float* __restrict__ bih_b, const float* __restrict__ bhh_b,
    float* __restrict__ pre) {
    int ns = blockIdx.x, g = blockIdx.y;
    int t = threadIdx.x;
    int w = t >> 6, l = t & 63, lc = l & 15, lk = l >> 4;
    int gn = ns * 128 + w * 16 + lc;
    const float* wrow = (gn < 512) ? (wih_f + (size_t)gn * cD)
                                   : (wih_b + (size_t)(gn - 512) * cD);
    const float* xb0 = x_seq + ((size_t)g * 32 + lc) * cD;
    const float* xb1 = x_seq + ((size_t)g * 32 + 16 + lc) * cD;
    f32x4 acc0 = {0.f, 0.f, 0.f, 0.f}, acc1 = {0.f, 0.f, 0.f, 0.f};
#pragma unroll
    for (int kf = 0; kf < 8; ++kf) {
        int ko = kf * 32 + lk * 8;
        bf16x8 a = cvt8(wrow + ko);
        bf16x8 b0 = cvt8(xb0 + ko);
        bf16x8 b1 = cvt8(xb1 + ko);
        acc0 = mfma16(a, b0, acc0);
        acc1 = mfma16(a, b1, acc1);
    }
    int nb = ns * 128 + w * 16 + lk * 4;
    float4 bv;
    if (nb < 512) {
        float4 u = *(const float4*)(bih_f + nb);
        float4 v = *(const float4*)(bhh_f + nb);
        bv = make_float4(u.x + v.x, u.y + v.y, u.z + v.z, u.w + v.w);
    } else {
        float4 u = *(const float4*)(bih_b + nb - 512);
        float4 v = *(const float4*)(bhh_b + nb - 512);
        bv = make_float4(u.x + v.x, u.y + v.y, u.z + v.z, u.w + v.w);
    }
    size_t base = ((size_t)g * 256 + (nb >> 2)) * 32;
    *(float4*)(pre + (base + lc) * 4) =
        make_float4(acc0[0] + bv.x, acc0[1] + bv.y, acc0[2] + bv.z, acc0[3] + bv.w);
    *(float4*)(pre + (base + 16 + lc) * 4) =
        make_float4(acc1[0] + bv.x, acc1[1] + bv.y, acc1[2] + bv.z, acc1[3] + bv.w);
}

// ---------------------------------------------------------------------------
// 3) MFMA LSTM v7: round-8 per-wave structure, but 2 blocks (= dir) x 1024 thr
//    = 16 waves = 4 waves/SIMD. Wave = (batch-half, h-block); per-wave state
//    unchanged (wf[4][4]=64 VGPR) -> no spill; 4 waves/SIMD fill the
//    dependency bubbles that limited the 2-wave/SIMD version.
__device__ __forceinline__ void lstm_step(
    f32x4 (&acc)[4], float (&cst)[4], const bf16x8 (&wf)[4][4],
    const unsigned short* __restrict__ hr, unsigned short* __restrict__ hw,
    const int (&rdo)[4], int wro,
    const float* __restrict__ preb, int gpre, bool dopre,
    unsigned short* __restrict__ hob, int g) {
    bf16x8 hf[4];
#pragma unroll
    for (int kf = 0; kf < 4; ++kf)
        hf[kf] = *(const bf16x8*)((const char*)hr + rdo[kf]);
#pragma unroll
    for (int kf = 0; kf < 4; ++kf)
#pragma unroll
        for (int q = 0; q < 4; ++q)
            acc[q] = mfma16(wf[q][kf], hf[kf], acc[q]);
    float hv[4];
#pragma unroll
    for (int r = 0; r < 4; ++r) {
        float ig = fsig(acc[0][r]);
        float fg = fsig(acc[1][r]);
        float gg = ftanh(acc[2][r]);
        float og = fsig(acc[3][r]);
        float cv = fg * cst[r] + ig * gg;
        cst[r] = cv;
        hv[r] = og * ftanh(cv);
    }
    if (dopre) {
#pragma unroll
        for (int q = 0; q < 4; ++q)
            acc[q] = *(const f32x4*)(preb + (size_t)gpre * 32768 + q * 4096);
    }
    unsigned int p0 = (unsigned int)f2bf(hv[0]) | ((unsigned int)f2bf(hv[1]) << 16);
    unsigned int p1 = (unsigned int)f2bf(hv[2]) | ((unsigned int)f2bf(hv[3]) << 16);
    *(uint2*)((char*)hw + wro) = make_uint2(p0, p1);
    *(uint2*)(hob + (size_t)g * 8192) = make_uint2(p0, p1);
    bar_lgkm();
}

__global__ __launch_bounds__(1024) void k_lstm_m(
    const float* __restrict__ pre,
    const float* __restrict__ whh_f, const float* __restrict__ whh_b,
    unsigned short* __restrict__ h_out) {
    __shared__ __align__(16) unsigned short hl[2][4096];  // [buf][b(32) x h(128)] bf16
    int t = threadIdx.x;
    int w16 = t >> 6;             // wave 0..15
    int bg = (w16 >> 3) * 16;     // batch half
    int w = w16 & 7;              // h-block owner
    int l = t & 63, lc = l & 15, lk = l >> 4;
    int dir = blockIdx.x;
    const float* whh = dir ? whh_b : whh_f;
    bf16x8 wf[4][4];
#pragma unroll
    for (int q = 0; q < 4; ++q) {
        int n = q * 128 + w * 16 + lc;
#pragma unroll
        for (int kf = 0; kf < 4; ++kf)
            wf[q][kf] = cvt8(whh + (size_t)n * 128 + kf * 32 + lk * 8);
    }
    // zero h(-1) buffer: 1024 threads x 8B = 8KB
    *(uint2*)&hl[1][t * 4] = make_uint2(0u, 0u);
    const float* preb = pre + ((size_t)(dir * 128 + w * 4 + lk) * 32 + (bg + lc)) * 4;
    unsigned short* hob = h_out + ((size_t)(dir * 32 + bg + lc) * 128 + w * 16 + lk * 4);
    // row = bg+lc (0..31); swizzle key = row & 15 = lc
    int rdo[4];
#pragma unroll
    for (int kf = 0; kf < 4; ++kf)
        rdo[kf] = ((bg + lc) * 256 + kf * 64 + lk * 16) ^ (lc << 4);
    int wro = ((bg + lc) * 256 + w * 32 + lk * 8) ^ (lc << 4);
    f32x4 accA[4], accB[4];
    float cst[4] = {0.f, 0.f, 0.f, 0.f};
    int g0 = dir ? 63 : 0;
    int sgn = dir ? -1 : 1;
#pragma unroll
    for (int q = 0; q < 4; ++q) accA[q] = *(const f32x4*)(preb + (size_t)g0 * 32768 + q * 4096);
#pragma unroll
    for (int q = 0; q < 4; ++q) accB[q] = *(const f32x4*)(preb + (size_t)(g0 + sgn) * 32768 + q * 4096);
    bar_lgkm();
    for (int s = 0; s < 64; s += 2) {
        int ga = g0 + sgn * s;
        lstm_step(accA, cst, wf, hl[1], hl[0], rdo, wro, preb, ga + 2 * sgn, s < 62, hob, ga);
        lstm_step(accB, cst, wf, hl[0], hl[1], rdo, wro, preb, ga + 3 * sgn, s < 61, hob, ga + sgn);
    }
}

// ---------------------------------------------------------------------------
// 4) gather(+sum over K) -> transposed hsumT[c][n]. 256 blocks = node.
__global__ __launch_bounds__(256) void k_gather(
    const int* __restrict__ idx, const int* __restrict__ p2g,
    const unsigned short* __restrict__ h_out, float* __restrict__ hsumT) {
    int bn = blockIdx.x;
    int b = bn >> 3;
    int t = threadIdx.x;
    int dirq = t >> 7, hh = t & 127;
    int l0 = idx[bn * cK + 0], l1 = idx[bn * cK + 1];
    int l2 = idx[bn * cK + 2], l3 = idx[bn * cK + 3];
    int g0 = p2g[b * cL + l0], g1 = p2g[b * cL + l1];
    int g2 = p2g[b * cL + l2], g3 = p2g[b * cL + l3];
    size_t ro = (size_t)(dirq * 32 + b) * 128 + hh;
    float a = bf2f(h_out[(size_t)g0 * 8192 + ro]) + bf2f(h_out[(size_t)g1 * 8192 + ro]) +
              bf2f(h_out[(size_t)g2 * 8192 + ro]) + bf2f(h_out[(size_t)g3 * 8192 + ro]);
    hsumT[(size_t)t * 256 + bn] = a;
}

// ---------------------------------------------------------------------------
// 5) fused projection + BatchNorm (verified).
__global__ __launch_bounds__(256) void k_proj_bn(
    const float* __restrict__ hsumT,
    const float* __restrict__ w_src, const float* __restrict__ b_src,
    const float* __restrict__ w_dst, const float* __restrict__ b_dst,
    const float* __restrict__ g_src, const float* __restrict__ bb_src,
    const float* __restrict__ g_dst, const float* __restrict__ bb_dst,
    float* __restrict__ hd_bn, float* __restrict__ tl_bn) {
    int which = blockIdx.x, c = blockIdx.y, t = threadIdx.x;
    __shared__ float ws[256];
    __shared__ float ssum[256], ssq[256];
    ws[t] = (which ? w_dst : w_src)[(size_t)c * cH + t];
    __syncthreads();
    float acc = (which ? b_dst : b_src)[c];
#pragma unroll 8
    for (int k = 0; k < cH; ++k)
        acc += ws[k] * hsumT[(size_t)k * 256 + t];
    ssum[t] = acc;
    ssq[t] = acc * acc;
    __syncthreads();
    for (int o = 128; o > 0; o >>= 1) {
        if (t < o) { ssum[t] += ssum[t + o]; ssq[t] += ssq[t + o]; }
        __syncthreads();
    }
    float mean = ssum[0] * (1.f / 256.f);
    float var = ssq[0] * (1.f / 256.f) - mean * mean;
    float gam = which ? g_dst[c] : g_src[c];
    float bet = which ? bb_dst[c] : bb_src[c];
    float scale = gam * rsqrtf(var + cEPS);
    (which ? tl_bn : hd_bn)[(size_t)t * cNI + c] = (acc - mean) * scale + bet;
}

// ---------------------------------------------------------------------------
// 6) MFMA NTL-A + fused lin (verified, unchanged).
__global__ __launch_bounds__(256, 2) void k_ntl_A(
    const float* __restrict__ hd_bn, const float* __restrict__ tl_bn,
    const float* __restrict__ ntl_w, const float* __restrict__ ntl_v,
    unsigned short* __restrict__ tmp,
    float* __restrict__ lsrc, float* __restrict__ ldst) {
    __shared__ __align__(16) unsigned short wl[128 * 128];
    __shared__ float vsh[256];
    int rh = blockIdx.x, t = threadIdx.x;
    int w = t >> 6, l = t & 63, lc = l & 15, lk = l >> 4;
    vsh[t] = ntl_v[(size_t)rh * 256 + t];
    {
        const float* wbase = ntl_w + (size_t)rh * 16384;
        int k = t >> 1, c0 = (t & 1) * 64;
        int sw = ((k >> 3) & 3) << 4;
#pragma unroll
        for (int u = 0; u < 8; ++u) {
            bf16x8 v = cvt8(wbase + k * 128 + c0 + u * 8);
            *(bf16x8*)((char*)wl + ((k * 256 + (c0 + u * 8) * 2) ^ sw)) = v;
        }
    }
    __syncthreads();
    {
        const float* hr = hd_bn + (size_t)t * cNI;
        const float* tr = tl_bn + (size_t)t * cNI;
        float a1 = 0.f, a2 = 0.f;
#pragma unroll 8
        for (int i = 0; i < cNI; i += 4) {
            float4 h4 = *(const float4*)(hr + i);
            float4 t4 = *(const float4*)(tr + i);
            a1 += h4.x * vsh[i] + h4.y * vsh[i + 1] + h4.z * vsh[i + 2] + h4.w * vsh[i + 3];
            a2 += t4.x * vsh[128 + i] + t4.y * vsh[128 + i + 1] + t4.z * vsh[128 + i + 2] + t4.w * vsh[128 + i + 3];
        }
        lsrc[(size_t)rh * 256 + t] = a1;
        ldst[(size_t)rh * 256 + t] = a2;
    }
    f32x4 acc[4][8] = {};
#pragma unroll
    for (int kf = 0; kf < 4; ++kf) {
        bf16x8 af[4];
#pragma unroll
        for (int mt = 0; mt < 4; ++mt) {
            int m = w * 64 + mt * 16 + lc;
            af[mt] = cvt8(hd_bn + (size_t)m * 128 + kf * 32 + lk * 8);
        }
#pragma unroll
        for (int nt = 0; nt < 8; ++nt) {
            int kb = (kf * 32 + lk * 8) * 256;
            int jb = (nt * 16 + lc) * 2;
            bf16x8 bv = *(const bf16x8*)((char*)wl + ((kb + jb) ^ (lk << 4)));
#pragma unroll
            for (int mt = 0; mt < 4; ++mt) acc[mt][nt] = mfma16(af[mt], bv, acc[mt][nt]);
        }
    }
#pragma unroll
    for (int mt = 0; mt < 4; ++mt) {
#pragma unroll
        for (int nt = 0; nt < 8; ++nt) {
            unsigned int lo = (unsigned int)f2bf(acc[mt][nt][0]) | ((unsigned int)f2bf(acc[mt][nt][1]) << 16);
            unsigned int hi = (unsigned int)f2bf(acc[mt][nt][2]) | ((unsigned int)f2bf(acc[mt][nt][3]) << 16);
            size_t off = (size_t)rh * 32768 + (size_t)((((w * 4 + mt) * 8 + nt) * 64 + l) * 4);
            *(uint2*)(tmp + off) = make_uint2(lo, hi);
        }
    }
}

// ---------------------------------------------------------------------------
// 7) bilinear + linear + bias -> pre2[rh][e], + BN partials (verified).
__global__ __launch_bounds__(64) void k_ntl_B(
    const unsigned short* __restrict__ tmp, const float* __restrict__ tl_bn,
    const float* __restrict__ lsrc, const float* __restrict__ ldst,
    const float* __restrict__ ntl_b, float* __restrict__ pre2,
    float2* __restrict__ part2) {
    int bgid = blockIdx.x;
    int rh = blockIdx.y;
    int t = threadIdx.x;
    int n0 = bgid * 32;
    __shared__ float tm[32][132];
    __shared__ float tl[32][132];
    {
        const uint4* src = (const uint4*)(tmp + (size_t)rh * 32768 +
                                          (size_t)(bgid >> 1) * 8192 + (size_t)(bgid & 1) * 4096);
#pragma unroll
        for (int rep = 0; rep < 8; ++rep) {
            int q = t + rep * 64;
            uint4 uv = src[q];
            unsigned int wds[4] = {uv.x, uv.y, uv.z, uv.w};
            int e0 = q * 8;
#pragma unroll
            for (int ui = 0; ui < 4; ++ui) {
                int e = e0 + ui * 2;
                int mt_l = e >> 11;
                int nt = (e >> 8) & 7;
                int ln = (e >> 2) & 63;
                int r = e & 3;
                int m = mt_l * 16 + (ln >> 4) * 4 + r;
                int j = nt * 16 + (ln & 15);
                tm[m][j] = bf2f((unsigned short)(wds[ui] & 0xffff));
                tm[m + 1][j] = bf2f((unsigned short)(wds[ui] >> 16));
            }
        }
#pragma unroll
        for (int rep = 0; rep < 4; ++rep) {
            int tt = t + rep * 64;
            int r = tt >> 3;
            int c0 = (tt & 7) * 16;
            const float4* fsrc = (const float4*)(tl_bn + (size_t)(n0 + r) * cNI + c0);
            float4 f0 = fsrc[0], f1 = fsrc[1], f2v = fsrc[2], f3 = fsrc[3];
            float* frow = &tl[r][c0];
            frow[0] = f0.x; frow[1] = f0.y; frow[2] = f0.z; frow[3] = f0.w;
            frow[4] = f1.x; frow[5] = f1.y; frow[6] = f1.z; frow[7] = f1.w;
            frow[8] = f2v.x; frow[9] = f2v.y; frow[10] = f2v.z; frow[11] = f2v.w;
            frow[12] = f3.x; frow[13] = f3.y; frow[14] = f3.z; frow[15] = f3.w;
        }
    }
    __syncthreads();
    int b_l = t >> 4, i2 = (t >> 2) & 3, j2 = t & 3;
    const float* ta0 = &tm[b_l * 8 + i2][0];
    const float* ta1 = &tm[b_l * 8 + i2 + 4][0];
    const float* tb0 = &tl[b_l * 8 + j2][0];
    const float* tb1 = &tl[b_l * 8 + j2 + 4][0];
    float s00 = 0.f, s01 = 0.f, s10 = 0.f, s11 = 0.f;
#pragma unroll 4
    for (int k = 0; k < 128; ++k) {
        float a0 = ta0[k], a1 = ta1[k], b0 = tb0[k], b1 = tb1[k];
        s00 += a0 * b0; s01 += a0 * b1; s10 += a1 * b0; s11 += a1 * b1;
    }
    int bglob = bgid * 4 + b_l;
    float nb = ntl_b[rh];
    const float* ls = lsrc + (size_t)rh * 256 + bglob * 8;
    const float* ld = ldst + (size_t)rh * 256 + bglob * 8;
    float* pr = pre2 + (size_t)rh * cE + bgid * 256 + b_l * 64;
    float vs[4];
    vs[0] = s00 + ls[i2] + ld[j2] + nb;
    vs[1] = s01 + ls[i2] + ld[j2 + 4] + nb;
    vs[2] = s10 + ls[i2 + 4] + ld[j2] + nb;
    vs[3] = s11 + ls[i2 + 4] + ld[j2 + 4] + nb;
    pr[i2 * 8 + j2] = vs[0];
    pr[i2 * 8 + j2 + 4] = vs[1];
    pr[(i2 + 4) * 8 + j2] = vs[2];
    pr[(i2 + 4) * 8 + j2 + 4] = vs[3];
    float sm = vs[0] + vs[1] + vs[2] + vs[3];
    float sq = vs[0] * vs[0] + vs[1] * vs[1] + vs[2] * vs[2] + vs[3] * vs[3];
#pragma unroll
    for (int o = 32; o > 0; o >>= 1) {
        sm += __shfl_down(sm, o);
        sq += __shfl_down(sq, o);
    }
    if (t == 0) part2[(size_t)rh * 8 + bgid] = make_float2(sm, sq);
}

// ---------------------------------------------------------------------------
// 8) logit + in-kernel BN2 + fused loss partials (verified).
__global__ __launch_bounds__(256) void k_final(
    const float* __restrict__ pre2, const float2* __restrict__ part2,
    const float* __restrict__ g2, const float* __restrict__ b2,
    const float* __restrict__ ntl_u, const int* __restrict__ mask,
    float* __restrict__ out, float* __restrict__ part) {
    int r = blockIdx.y, et = blockIdx.x;
    int t = threadIdx.x;
    __shared__ float sc[32], sh[32];
    {
        int rh_l = t >> 3, slot = t & 7;
        int rh = r * 32 + rh_l;
        float2 pp = part2[(size_t)rh * 8 + slot];
        float S = pp.x, Q = pp.y;
        S += __shfl_xor(S, 1); Q += __shfl_xor(Q, 1);
        S += __shfl_xor(S, 2); Q += __shfl_xor(Q, 2);
        S += __shfl_xor(S, 4); Q += __shfl_xor(Q, 4);
        if (slot == 0) {
            float mean = S * (1.f / 2048.f);
            float var = Q * (1.f / 2048.f) - mean * mean;
            float scv = g2[rh] * rsqrtf(var + cEPS);
            sc[rh_l] = scv;
            sh[rh_l] = b2[rh] - mean * scv;
        }
    }
    __syncthreads();
    int e = et * 256 + t;
    float a = 0.f;
#pragma unroll
    for (int h = 0; h < 32; ++h) {
        int rh = r * 32 + h;
        float p = pre2[(size_t)rh * cE + e];
        a += ntl_u[rh] * ftanh(fmaf(p, sc[h], sh[h]));
    }
    out[(size_t)e * 16 + r] = a;
    int m = mask[(size_t)e * 16 + r];
    bool mb = (m != 0);
    bool eq = ((a > 0.f) == mb);
    float nll = mb ? nls(a) : -logf(1.f / (1.f + expf(a)) + 1e-5f);
    float corr = eq ? 1.f : 0.f;
    unsigned long long bal = __ballot(eq);
    float em = (bal == ~0ull) ? 1.f : 0.f;
#pragma unroll
    for (int o = 32; o > 0; o >>= 1) {
        nll += __shfl_down(nll, o);
        corr += __shfl_down(corr, o);
    }
    if ((t & 63) == 0) {
        int bg = et * 4 + (t >> 6);
        float* p = part + ((size_t)bg * 16 + r) * 4;
        p[0] = nll; p[1] = corr; p[2] = em;
    }
}

// ---------------------------------------------------------------------------
// 9) final loss reduction
__global__ void k_loss_fin(const float* __restrict__ part, float* __restrict__ out) {
    int t = threadIdx.x;
    float nll = 0.f, corr = 0.f, em = 0.f;
    if (t < 32) {
        em = 1.f;
        for (int r = 0; r < 16; ++r) {
            const float* p = part + ((size_t)t * 16 + r) * 4;
            nll += p[0]; corr += p[1]; em = fminf(em, p[2]);
        }
    }
#pragma unroll
    for (int o = 32; o > 0; o >>= 1) {
        nll += __shfl_down(nll, o);
        corr += __shfl_down(corr, o);
        em += __shfl_down(em, o);
    }
    if (t == 0) {
        out[32768] = nll / 32.f;
        out[32769] = corr / 32768.f;
        out[32770] = em / 32.f;
    }
}

}  // namespace

extern "C" void kernel_launch(void* const* d_in, const int* in_sizes, int n_in,
                              void* d_out, int out_size, void* d_ws, size_t ws_size,
                              hipStream_t stream) {
    (void)in_sizes; (void)n_in; (void)out_size; (void)ws_size;
    const int* seq = (const int*)d_in[0];
    const int* p2g = (const int*)d_in[1];
    const int* idx = (const int*)d_in[2];
    const int* mask = (const int*)d_in[5];
    const float* emb = (const float*)d_in[6];
    const float* wih_f = (const float*)d_in[7];
    const float* whh_f = (const float*)d_in[8];
    const float* bih_f = (const float*)d_in[9];
    const float* bhh_f = (const float*)d_in[10];
    const float* wih_b = (const float*)d_in[11];
    const float* whh_b = (const float*)d_in[12];
    const float* bih_b = (const float*)d_in[13];
    const float* bhh_b = (const float*)d_in[14];
    const float* lsw = (const float*)d_in[15];
    const float* lsb = (const float*)d_in[16];
    const float* ldw = (const float*)d_in[17];
    const float* ldb = (const float*)d_in[18];
    const float* bn_sg = (const float*)d_in[19];
    const float* bn_sb = (const float*)d_in[20];
    const float* bn_dg = (const float*)d_in[21];
    const float* bn_db = (const float*)d_in[22];
    const float* ntlw = (const float*)d_in[23];
    const float* ntlv = (const float*)d_in[24];
    const float* ntlb = (const float*)d_in[25];
    const float* ntlu = (const float*)d_in[26];
    const float* bn2g = (const float*)d_in[27];
    const float* bn2b = (const float*)d_in[28];
    float* out = (float*)d_out;
    char* ws = (char*)d_ws;

    float* x_seq = (float*)(ws + 0);
    float* pre = (float*)(ws + 2097152);
    unsigned short* tmp = (unsigned short*)(ws + 0);
    size_t off = 33554432;
    unsigned short* h_out = (unsigned short*)(ws + off); off += 1048576;
    float* hsumT = (float*)(ws + off); off += 262144;
    float* hd_bn = (float*)(ws + off); off += 131072;
    float* tl_bn = (float*)(ws + off); off += 131072;
    float* lsrc = (float*)(ws + off); off += 524288;
    float* ldst = (float*)(ws + off); off += 524288;
    float* pre2 = (float*)(ws + off); off += 4194304;
    float2* part2 = (float2*)(ws + off); off += 32768;
    float* part = (float*)(ws + off); off += 8192;

    k_embed<<<32, 256, 0, stream>>>(seq, p2g, emb, x_seq);
    k_gemm_in<<<dim3(8, 64), 512, 0, stream>>>(x_seq, wih_f, wih_b, bih_f, bhh_f, bih_b, bhh_b, pre);
    k_lstm_m<<<2, 1024, 0, stream>>>(pre, whh_f, whh_b, h_out);
    k_gather<<<256, 256, 0, stream>>>(idx, p2g, h_out, hsumT);
    k_proj_bn<<<dim3(2, 128), 256, 0, stream>>>(hsumT, lsw, lsb, ldw, ldb,
                                                bn_sg, bn_sb, bn_dg, bn_db, hd_bn, tl_bn);
    k_ntl_A<<<512, 256, 0, stream>>>(hd_bn, tl_bn, ntlw, ntlv, tmp, lsrc, ldst);
    k_ntl_B<<<dim3(8, 512), 64, 0, stream>>>(tmp, tl_bn, lsrc, ldst, ntlb, pre2, part2);
    k_final<<<dim3(8, 16), 256, 0, stream>>>(pre2, part2, bn2g, bn2b, ntlu, mask, out, part);
    k_loss_fin<<<1, 64, 0, stream>>>(part, out);
}

// Round 12
// 236.186 us; speedup vs baseline: 1.1630x; 1.0329x over previous
//
#include <hip/hip_runtime.h>
#include <math.h>

namespace {

constexpr int cB = 32, cL = 128, cG = 64, cD = 256;
constexpr int cHD = 128, cH = 256;
constexpr int cN = 8, cK = 4;
constexpr int cNI = 128, cRH = 512;
constexpr int cE = 2048;
constexpr float cEPS = 1e-5f;

typedef __bf16 bf16x8 __attribute__((ext_vector_type(8)));
typedef float f32x4 __attribute__((ext_vector_type(4)));

__device__ __forceinline__ f32x4 mfma16(bf16x8 a, bf16x8 b, f32x4 c) {
    return __builtin_amdgcn_mfma_f32_16x16x32_bf16(a, b, c, 0, 0, 0);
}

__device__ __forceinline__ float bf2f(unsigned short u) {
    unsigned int x = ((unsigned int)u) << 16;
    return __uint_as_float(x);
}
__device__ __forceinline__ unsigned short f2bf(float f) {
    unsigned int x = __float_as_uint(f);
    unsigned int r = (x + 0x7fffu + ((x >> 16) & 1u)) >> 16;  // RNE
    return (unsigned short)r;
}
// unpack a u32 holding 2 bf16 (lo = elem k, hi = elem k+1)
__device__ __forceinline__ void bfp(unsigned int u, float& lo, float& hi) {
    lo = __uint_as_float(u << 16);
    hi = __uint_as_float(u & 0xffff0000u);
}
__device__ __forceinline__ float frcp(float x) { return __builtin_amdgcn_rcpf(x); }
__device__ __forceinline__ float fsig(float x) { return frcp(1.f + __expf(-x)); }
__device__ __forceinline__ float ftanh(float x) { return 1.f - 2.f * frcp(__expf(2.f * x) + 1.f); }
__device__ __forceinline__ float nls(float x) {
    return (x >= 0.f) ? log1pf(expf(-x)) : (log1pf(expf(x)) - x);
}
__device__ __forceinline__ bf16x8 cvt8(const float* __restrict__ p) {
    float4 a = *(const float4*)p, b = *(const float4*)(p + 4);
    bf16x8 v;
    v[0] = (__bf16)a.x; v[1] = (__bf16)a.y; v[2] = (__bf16)a.z; v[3] = (__bf16)a.w;
    v[4] = (__bf16)b.x; v[5] = (__bf16)b.y; v[6] = (__bf16)b.z; v[7] = (__bf16)b.w;
    return v;
}

// lgkm-only barrier: LDS ping-pong needs lgkmcnt ordering, NOT a vmcnt(0) drain.
__device__ __forceinline__ void bar_lgkm() {
    asm volatile("s_waitcnt lgkmcnt(0)\n\ts_barrier" ::: "memory");
}

// ---------------------------------------------------------------------------
// 1) token embedding + scatter_sum (verified).
__global__ __launch_bounds__(256) void k_embed(
    const int* __restrict__ seq, const int* __restrict__ p2g,
    const float* __restrict__ emb, float* __restrict__ x_seq) {
    __shared__ float xl[cG * cD];
    __shared__ int toks[cL], grps[cL];
    int b = blockIdx.x, t = threadIdx.x;
    if (t < 128) toks[t] = seq[b * cL + t];
    else grps[t - 128] = p2g[b * cL + (t - 128)];
    for (int g = 0; g < cG; ++g) xl[g * cD + t] = 0.f;
    __syncthreads();
    for (int l = 0; l < cL; l += 4) {
        float v0 = emb[(size_t)toks[l + 0] * cD + t];
        float v1 = emb[(size_t)toks[l + 1] * cD + t];
        float v2 = emb[(size_t)toks[l + 2] * cD + t];
        float v3 = emb[(size_t)toks[l + 3] * cD + t];
        xl[grps[l + 0] * cD + t] += v0;
        xl[grps[l + 1] * cD + t] += v1;
        xl[grps[l + 2] * cD + t] += v2;
        xl[grps[l + 3] * cD + t] += v3;
    }
    for (int g = 0; g < cG; ++g)
        x_seq[(g * cB + b) * cD + t] = xl[g * cD + t];
}

// ---------------------------------------------------------------------------
// 2) LSTM input GEMM via MFMA (verified).
__global__ __launch_bounds__(512) void k_gemm_in(
    const float* __restrict__ x_seq,
    const float* __restrict__ wih_f, const float* __restrict__ wih_b,
    const float* __restrict__ bih_f, const float* __restrict__ bhh_f,
    const float* __restrict__ bih_b, const float* __restrict__ bhh_b,
    float* __restrict__ pre) {
    int ns = blockIdx.x, g = blockIdx.y;
    int t = threadIdx.x;
    int w = t >> 6, l = t & 63, lc = l & 15, lk = l >> 4;
    int gn = ns * 128 + w * 16 + lc;
    const float* wrow = (gn < 512) ? (wih_f + (size_t)gn * cD)
                                   : (wih_b + (size_t)(gn - 512) * cD);
    const float* xb0 = x_seq + ((size_t)g * 32 + lc) * cD;
    const float* xb1 = x_seq + ((size_t)g * 32 + 16 + lc) * cD;
    f32x4 acc0 = {0.f, 0.f, 0.f, 0.f}, acc1 = {0.f, 0.f, 0.f, 0.f};
#pragma unroll
    for (int kf = 0; kf < 8; ++kf) {
        int ko = kf * 32 + lk * 8;
        bf16x8 a = cvt8(wrow + ko);
        bf16x8 b0 = cvt8(xb0 + ko);
        bf16x8 b1 = cvt8(xb1 + ko);
        acc0 = mfma16(a, b0, acc0);
        acc1 = mfma16(a, b1, acc1);
    }
    int nb = ns * 128 + w * 16 + lk * 4;
    float4 bv;
    if (nb < 512) {
        float4 u = *(const float4*)(bih_f + nb);
        float4 v = *(const float4*)(bhh_f + nb);
        bv = make_float4(u.x + v.x, u.y + v.y, u.z + v.z, u.w + v.w);
    } else {
        float4 u = *(const float4*)(bih_b + nb - 512);
        float4 v = *(const float4*)(bhh_b + nb - 512);
        bv = make_float4(u.x + v.x, u.y + v.y, u.z + v.z, u.w + v.w);
    }
    size_t base = ((size_t)g * 256 + (nb >> 2)) * 32;
    *(float4*)(pre + (base + lc) * 4) =
        make_float4(acc0[0] + bv.x, acc0[1] + bv.y, acc0[2] + bv.z, acc0[3] + bv.w);
    *(float4*)(pre + (base + 16 + lc) * 4) =
        make_float4(acc1[0] + bv.x, acc1[1] + bv.y, acc1[2] + bv.z, acc1[3] + bv.w);
}

// ---------------------------------------------------------------------------
// 3) MFMA LSTM v8: round-11 structure (2 blocks = dir, 1024 thr = 16 waves =
//    4 waves/SIMD) but with __launch_bounds__(1024, 4) -> VGPR cap 128 (we
//    need ~76) so NO spill (round 11's 64-cap spilled, WRITE_SIZE 1200KB).
__device__ __forceinline__ void lstm_step(
    f32x4 (&acc)[4], float (&cst)[4], const bf16x8 (&wf)[4][4],
    const unsigned short* __restrict__ hr, unsigned short* __restrict__ hw,
    const int (&rdo)[4], int wro,
    const float* __restrict__ preb, int gpre, bool dopre,
    unsigned short* __restrict__ hob, int g) {
    bf16x8 hf[4];
#pragma unroll
    for (int kf = 0; kf < 4; ++kf)
        hf[kf] = *(const bf16x8*)((const char*)hr + rdo[kf]);
#pragma unroll
    for (int kf = 0; kf < 4; ++kf)
#pragma unroll
        for (int q = 0; q < 4; ++q)
            acc[q] = mfma16(wf[q][kf], hf[kf], acc[q]);
    float hv[4];
#pragma unroll
    for (int r = 0; r < 4; ++r) {
        float ig = fsig(acc[0][r]);
        float fg = fsig(acc[1][r]);
        float gg = ftanh(acc[2][r]);
        float og = fsig(acc[3][r]);
        float cv = fg * cst[r] + ig * gg;
        cst[r] = cv;
        hv[r] = og * ftanh(cv);
    }
    if (dopre) {
#pragma unroll
        for (int q = 0; q < 4; ++q)
            acc[q] = *(const f32x4*)(preb + (size_t)gpre * 32768 + q * 4096);
    }
    unsigned int p0 = (unsigned int)f2bf(hv[0]) | ((unsigned int)f2bf(hv[1]) << 16);
    unsigned int p1 = (unsigned int)f2bf(hv[2]) | ((unsigned int)f2bf(hv[3]) << 16);
    *(uint2*)((char*)hw + wro) = make_uint2(p0, p1);
    *(uint2*)(hob + (size_t)g * 8192) = make_uint2(p0, p1);
    bar_lgkm();
}

__global__ __launch_bounds__(1024, 4) void k_lstm_m(
    const float* __restrict__ pre,
    const float* __restrict__ whh_f, const float* __restrict__ whh_b,
    unsigned short* __restrict__ h_out) {
    __shared__ __align__(16) unsigned short hl[2][4096];  // [buf][b(32) x h(128)] bf16
    int t = threadIdx.x;
    int w16 = t >> 6;             // wave 0..15
    int bg = (w16 >> 3) * 16;     // batch half
    int w = w16 & 7;              // h-block owner
    int l = t & 63, lc = l & 15, lk = l >> 4;
    int dir = blockIdx.x;
    const float* whh = dir ? whh_b : whh_f;
    bf16x8 wf[4][4];
#pragma unroll
    for (int q = 0; q < 4; ++q) {
        int n = q * 128 + w * 16 + lc;
#pragma unroll
        for (int kf = 0; kf < 4; ++kf)
            wf[q][kf] = cvt8(whh + (size_t)n * 128 + kf * 32 + lk * 8);
    }
    *(uint2*)&hl[1][t * 4] = make_uint2(0u, 0u);
    const float* preb = pre + ((size_t)(dir * 128 + w * 4 + lk) * 32 + (bg + lc)) * 4;
    unsigned short* hob = h_out + ((size_t)(dir * 32 + bg + lc) * 128 + w * 16 + lk * 4);
    int rdo[4];
#pragma unroll
    for (int kf = 0; kf < 4; ++kf)
        rdo[kf] = ((bg + lc) * 256 + kf * 64 + lk * 16) ^ (lc << 4);
    int wro = ((bg + lc) * 256 + w * 32 + lk * 8) ^ (lc << 4);
    f32x4 accA[4], accB[4];
    float cst[4] = {0.f, 0.f, 0.f, 0.f};
    int g0 = dir ? 63 : 0;
    int sgn = dir ? -1 : 1;
#pragma unroll
    for (int q = 0; q < 4; ++q) accA[q] = *(const f32x4*)(preb + (size_t)g0 * 32768 + q * 4096);
#pragma unroll
    for (int q = 0; q < 4; ++q) accB[q] = *(const f32x4*)(preb + (size_t)(g0 + sgn) * 32768 + q * 4096);
    bar_lgkm();
    for (int s = 0; s < 64; s += 2) {
        int ga = g0 + sgn * s;
        lstm_step(accA, cst, wf, hl[1], hl[0], rdo, wro, preb, ga + 2 * sgn, s < 62, hob, ga);
        lstm_step(accB, cst, wf, hl[0], hl[1], rdo, wro, preb, ga + 3 * sgn, s < 61, hob, ga + sgn);
    }
}

// ---------------------------------------------------------------------------
// 4) gather(+sum over K) -> transposed hsumT[c][n] (verified).
__global__ __launch_bounds__(256) void k_gather(
    const int* __restrict__ idx, const int* __restrict__ p2g,
    const unsigned short* __restrict__ h_out, float* __restrict__ hsumT) {
    int bn = blockIdx.x;
    int b = bn >> 3;
    int t = threadIdx.x;
    int dirq = t >> 7, hh = t & 127;
    int l0 = idx[bn * cK + 0], l1 = idx[bn * cK + 1];
    int l2 = idx[bn * cK + 2], l3 = idx[bn * cK + 3];
    int g0 = p2g[b * cL + l0], g1 = p2g[b * cL + l1];
    int g2 = p2g[b * cL + l2], g3 = p2g[b * cL + l3];
    size_t ro = (size_t)(dirq * 32 + b) * 128 + hh;
    float a = bf2f(h_out[(size_t)g0 * 8192 + ro]) + bf2f(h_out[(size_t)g1 * 8192 + ro]) +
              bf2f(h_out[(size_t)g2 * 8192 + ro]) + bf2f(h_out[(size_t)g3 * 8192 + ro]);
    hsumT[(size_t)t * 256 + bn] = a;
}

// ---------------------------------------------------------------------------
// 5) fused projection + BatchNorm; dst side also emits bf16 copy for ntl_B.
__global__ __launch_bounds__(256) void k_proj_bn(
    const float* __restrict__ hsumT,
    const float* __restrict__ w_src, const float* __restrict__ b_src,
    const float* __restrict__ w_dst, const float* __restrict__ b_dst,
    const float* __restrict__ g_src, const float* __restrict__ bb_src,
    const float* __restrict__ g_dst, const float* __restrict__ bb_dst,
    float* __restrict__ hd_bn, float* __restrict__ tl_bn,
    unsigned short* __restrict__ tl_bf) {
    int which = blockIdx.x, c = blockIdx.y, t = threadIdx.x;
    __shared__ float ws[256];
    __shared__ float ssum[256], ssq[256];
    ws[t] = (which ? w_dst : w_src)[(size_t)c * cH + t];
    __syncthreads();
    float acc = (which ? b_dst : b_src)[c];
#pragma unroll 8
    for (int k = 0; k < cH; ++k)
        acc += ws[k] * hsumT[(size_t)k * 256 + t];
    ssum[t] = acc;
    ssq[t] = acc * acc;
    __syncthreads();
    for (int o = 128; o > 0; o >>= 1) {
        if (t < o) { ssum[t] += ssum[t + o]; ssq[t] += ssq[t + o]; }
        __syncthreads();
    }
    float mean = ssum[0] * (1.f / 256.f);
    float var = ssq[0] * (1.f / 256.f) - mean * mean;
    float gam = which ? g_dst[c] : g_src[c];
    float bet = which ? bb_dst[c] : bb_src[c];
    float scale = gam * rsqrtf(var + cEPS);
    float val = (acc - mean) * scale + bet;
    (which ? tl_bn : hd_bn)[(size_t)t * cNI + c] = val;
    if (which) tl_bf[(size_t)t * cNI + c] = f2bf(val);
}

// ---------------------------------------------------------------------------
// 6) MFMA NTL-A + fused lin (verified, unchanged).
__global__ __launch_bounds__(256, 2) void k_ntl_A(
    const float* __restrict__ hd_bn, const float* __restrict__ tl_bn,
    const float* __restrict__ ntl_w, const float* __restrict__ ntl_v,
    unsigned short* __restrict__ tmp,
    float* __restrict__ lsrc, float* __restrict__ ldst) {
    __shared__ __align__(16) unsigned short wl[128 * 128];
    __shared__ float vsh[256];
    int rh = blockIdx.x, t = threadIdx.x;
    int w = t >> 6, l = t & 63, lc = l & 15, lk = l >> 4;
    vsh[t] = ntl_v[(size_t)rh * 256 + t];
    {
        const float* wbase = ntl_w + (size_t)rh * 16384;
        int k = t >> 1, c0 = (t & 1) * 64;
        int sw = ((k >> 3) & 3) << 4;
#pragma unroll
        for (int u = 0; u < 8; ++u) {
            bf16x8 v = cvt8(wbase + k * 128 + c0 + u * 8);
            *(bf16x8*)((char*)wl + ((k * 256 + (c0 + u * 8) * 2) ^ sw)) = v;
        }
    }
    __syncthreads();
    {
        const float* hr = hd_bn + (size_t)t * cNI;
        const float* tr = tl_bn + (size_t)t * cNI;
        float a1 = 0.f, a2 = 0.f;
#pragma unroll 8
        for (int i = 0; i < cNI; i += 4) {
            float4 h4 = *(const float4*)(hr + i);
            float4 t4 = *(const float4*)(tr + i);
            a1 += h4.x * vsh[i] + h4.y * vsh[i + 1] + h4.z * vsh[i + 2] + h4.w * vsh[i + 3];
            a2 += t4.x * vsh[128 + i] + t4.y * vsh[128 + i + 1] + t4.z * vsh[128 + i + 2] + t4.w * vsh[128 + i + 3];
        }
        lsrc[(size_t)rh * 256 + t] = a1;
        ldst[(size_t)rh * 256 + t] = a2;
    }
    f32x4 acc[4][8] = {};
#pragma unroll
    for (int kf = 0; kf < 4; ++kf) {
        bf16x8 af[4];
#pragma unroll
        for (int mt = 0; mt < 4; ++mt) {
            int m = w * 64 + mt * 16 + lc;
            af[mt] = cvt8(hd_bn + (size_t)m * 128 + kf * 32 + lk * 8);
        }
#pragma unroll
        for (int nt = 0; nt < 8; ++nt) {
            int kb = (kf * 32 + lk * 8) * 256;
            int jb = (nt * 16 + lc) * 2;
            bf16x8 bv = *(const bf16x8*)((char*)wl + ((kb + jb) ^ (lk << 4)));
#pragma unroll
            for (int mt = 0; mt < 4; ++mt) acc[mt][nt] = mfma16(af[mt], bv, acc[mt][nt]);
        }
    }
#pragma unroll
    for (int mt = 0; mt < 4; ++mt) {
#pragma unroll
        for (int nt = 0; nt < 8; ++nt) {
            unsigned int lo = (unsigned int)f2bf(acc[mt][nt][0]) | ((unsigned int)f2bf(acc[mt][nt][1]) << 16);
            unsigned int hi = (unsigned int)f2bf(acc[mt][nt][2]) | ((unsigned int)f2bf(acc[mt][nt][3]) << 16);
            size_t off = (size_t)rh * 32768 + (size_t)((((w * 4 + mt) * 8 + nt) * 64 + l) * 4);
            *(uint2*)(tmp + off) = make_uint2(lo, hi);
        }
    }
}

// ---------------------------------------------------------------------------
// 7) bilinear + linear + bias -> pre2[rh][e], + BN partials.
//    v2: bf16 LDS tiles (17.4KB -> 9 blocks/CU, was 33.8KB -> 4) and
//    uint2-packed reads (128 LDS instr/wave, was 512).
__global__ __launch_bounds__(64) void k_ntl_B(
    const unsigned short* __restrict__ tmp, const unsigned short* __restrict__ tl_bf,
    const float* __restrict__ lsrc, const float* __restrict__ ldst,
    const float* __restrict__ ntl_b, float* __restrict__ pre2,
    float2* __restrict__ part2) {
    int bgid = blockIdx.x;
    int rh = blockIdx.y;
    int t = threadIdx.x;
    int n0 = bgid * 32;
    __shared__ unsigned short tm[32][136];  // 8704 B, +8-short pad vs bank stride
    __shared__ unsigned short tl[32][136];
    {
        const uint4* src = (const uint4*)(tmp + (size_t)rh * 32768 +
                                          (size_t)(bgid >> 1) * 8192 + (size_t)(bgid & 1) * 4096);
#pragma unroll
        for (int rep = 0; rep < 8; ++rep) {
            int q = t + rep * 64;
            uint4 uv = src[q];
            unsigned int wds[4] = {uv.x, uv.y, uv.z, uv.w};
            int e0 = q * 8;
#pragma unroll
            for (int ui = 0; ui < 4; ++ui) {
                int e = e0 + ui * 2;
                int mt_l = e >> 11;
                int nt = (e >> 8) & 7;
                int ln = (e >> 2) & 63;
                int r = e & 3;
                int m = mt_l * 16 + (ln >> 4) * 4 + r;
                int j = nt * 16 + (ln & 15);
                tm[m][j] = (unsigned short)(wds[ui] & 0xffffu);
                tm[m + 1][j] = (unsigned short)(wds[ui] >> 16);
            }
        }
        // tl: 32 rows x 128 bf16 from global, coalesced 16B chunks
        int row = t >> 1, c0 = (t & 1) * 64;
        const uint4* fsrc = (const uint4*)(tl_bf + (size_t)(n0 + row) * cNI + c0);
#pragma unroll
        for (int u = 0; u < 8; ++u) {
            uint4 v = fsrc[u];
            *(uint4*)&tl[row][c0 + u * 8] = v;
        }
    }
    __syncthreads();
    int b_l = t >> 4, i2 = (t >> 2) & 3, j2 = t & 3;
    const unsigned short* ta0 = &tm[b_l * 8 + i2][0];
    const unsigned short* ta1 = &tm[b_l * 8 + i2 + 4][0];
    const unsigned short* tb0 = &tl[b_l * 8 + j2][0];
    const unsigned short* tb1 = &tl[b_l * 8 + j2 + 4][0];
    float s00 = 0.f, s01 = 0.f, s10 = 0.f, s11 = 0.f;
#pragma unroll 4
    for (int k4 = 0; k4 < 32; ++k4) {
        uint2 ua0 = *(const uint2*)&ta0[k4 * 4];
        uint2 ua1 = *(const uint2*)&ta1[k4 * 4];
        uint2 ub0 = *(const uint2*)&tb0[k4 * 4];
        uint2 ub1 = *(const uint2*)&tb1[k4 * 4];
        float a0l, a0h, a1l, a1h, b0l, b0h, b1l, b1h;
        bfp(ua0.x, a0l, a0h); bfp(ua1.x, a1l, a1h);
        bfp(ub0.x, b0l, b0h); bfp(ub1.x, b1l, b1h);
        s00 += a0l * b0l + a0h * b0h;
        s01 += a0l * b1l + a0h * b1h;
        s10 += a1l * b0l + a1h * b0h;
        s11 += a1l * b1l + a1h * b1h;
        bfp(ua0.y, a0l, a0h); bfp(ua1.y, a1l, a1h);
        bfp(ub0.y, b0l, b0h); bfp(ub1.y, b1l, b1h);
        s00 += a0l * b0l + a0h * b0h;
        s01 += a0l * b1l + a0h * b1h;
        s10 += a1l * b0l + a1h * b0h;
        s11 += a1l * b1l + a1h * b1h;
    }
    int bglob = bgid * 4 + b_l;
    float nb = ntl_b[rh];
    const float* ls = lsrc + (size_t)rh * 256 + bglob * 8;
    const float* ld = ldst + (size_t)rh * 256 + bglob * 8;
    float* pr = pre2 + (size_t)rh * cE + bgid * 256 + b_l * 64;
    float vs[4];
    vs[0] = s00 + ls[i2] + ld[j2] + nb;
    vs[1] = s01 + ls[i2] + ld[j2 + 4] + nb;
    vs[2] = s10 + ls[i2 + 4] + ld[j2] + nb;
    vs[3] = s11 + ls[i2 + 4] + ld[j2 + 4] + nb;
    pr[i2 * 8 + j2] = vs[0];
    pr[i2 * 8 + j2 + 4] = vs[1];
    pr[(i2 + 4) * 8 + j2] = vs[2];
    pr[(i2 + 4) * 8 + j2 + 4] = vs[3];
    float sm = vs[0] + vs[1] + vs[2] + vs[3];
    float sq = vs[0] * vs[0] + vs[1] * vs[1] + vs[2] * vs[2] + vs[3] * vs[3];
#pragma unroll
    for (int o = 32; o > 0; o >>= 1) {
        sm += __shfl_down(sm, o);
        sq += __shfl_down(sq, o);
    }
    if (t == 0) part2[(size_t)rh * 8 + bgid] = make_float2(sm, sq);
}

// ---------------------------------------------------------------------------
// 8) logit + in-kernel BN2 + fused loss partials (verified).
__global__ __launch_bounds__(256) void k_final(
    const float* __restrict__ pre2, const float2* __restrict__ part2,
    const float* __restrict__ g2, const float* __restrict__ b2,
    const float* __restrict__ ntl_u, const int* __restrict__ mask,
    float* __restrict__ out, float* __restrict__ part) {
    int r = blockIdx.y, et = blockIdx.x;
    int t = threadIdx.x;
    __shared__ float sc[32], sh[32];
    {
        int rh_l = t >> 3, slot = t & 7;
        int rh = r * 32 + rh_l;
        float2 pp = part2[(size_t)rh * 8 + slot];
        float S = pp.x, Q = pp.y;
        S += __shfl_xor(S, 1); Q += __shfl_xor(Q, 1);
        S += __shfl_xor(S, 2); Q += __shfl_xor(Q, 2);
        S += __shfl_xor(S, 4); Q += __shfl_xor(Q, 4);
        if (slot == 0) {
            float mean = S * (1.f / 2048.f);
            float var = Q * (1.f / 2048.f) - mean * mean;
            float scv = g2[rh] * rsqrtf(var + cEPS);
            sc[rh_l] = scv;
            sh[rh_l] = b2[rh] - mean * scv;
        }
    }
    __syncthreads();
    int e = et * 256 + t;
    float a = 0.f;
#pragma unroll
    for (int h = 0; h < 32; ++h) {
        int rh = r * 32 + h;
        float p = pre2[(size_t)rh * cE + e];
        a += ntl_u[rh] * ftanh(fmaf(p, sc[h], sh[h]));
    }
    out[(size_t)e * 16 + r] = a;
    int m = mask[(size_t)e * 16 + r];
    bool mb = (m != 0);
    bool eq = ((a > 0.f) == mb);
    float nll = mb ? nls(a) : -logf(1.f / (1.f + expf(a)) + 1e-5f);
    float corr = eq ? 1.f : 0.f;
    unsigned long long bal = __ballot(eq);
    float em = (bal == ~0ull) ? 1.f : 0.f;
#pragma unroll
    for (int o = 32; o > 0; o >>= 1) {
        nll += __shfl_down(nll, o);
        corr += __shfl_down(corr, o);
    }
    if ((t & 63) == 0) {
        int bg = et * 4 + (t >> 6);
        float* p = part + ((size_t)bg * 16 + r) * 4;
        p[0] = nll; p[1] = corr; p[2] = em;
    }
}

// ---------------------------------------------------------------------------
// 9) final loss reduction
__global__ void k_loss_fin(const float* __restrict__ part, float* __restrict__ out) {
    int t = threadIdx.x;
    float nll = 0.f, corr = 0.f, em = 0.f;
    if (t < 32) {
        em = 1.f;
        for (int r = 0; r < 16; ++r) {
            const float* p = part + ((size_t)t * 16 + r) * 4;
            nll += p[0]; corr += p[1]; em = fminf(em, p[2]);
        }
    }
#pragma unroll
    for (int o = 32; o > 0; o >>= 1) {
        nll += __shfl_down(nll, o);
        corr += __shfl_down(corr, o);
        em += __shfl_down(em, o);
    }
    if (t == 0) {
        out[32768] = nll / 32.f;
        out[32769] = corr / 32768.f;
        out[32770] = em / 32.f;
    }
}

}  // namespace

extern "C" void kernel_launch(void* const* d_in, const int* in_sizes, int n_in,
                              void* d_out, int out_size, void* d_ws, size_t ws_size,
                              hipStream_t stream) {
    (void)in_sizes; (void)n_in; (void)out_size; (void)ws_size;
    const int* seq = (const int*)d_in[0];
    const int* p2g = (const int*)d_in[1];
    const int* idx = (const int*)d_in[2];
    const int* mask = (const int*)d_in[5];
    const float* emb = (const float*)d_in[6];
    const float* wih_f = (const float*)d_in[7];
    const float* whh_f = (const float*)d_in[8];
    const float* bih_f = (const float*)d_in[9];
    const float* bhh_f = (const float*)d_in[10];
    const float* wih_b = (const float*)d_in[11];
    const float* whh_b = (const float*)d_in[12];
    const float* bih_b = (const float*)d_in[13];
    const float* bhh_b = (const float*)d_in[14];
    const float* lsw = (const float*)d_in[15];
    const float* lsb = (const float*)d_in[16];
    const float* ldw = (const float*)d_in[17];
    const float* ldb = (const float*)d_in[18];
    const float* bn_sg = (const float*)d_in[19];
    const float* bn_sb = (const float*)d_in[20];
    const float* bn_dg = (const float*)d_in[21];
    const float* bn_db = (const float*)d_in[22];
    const float* ntlw = (const float*)d_in[23];
    const float* ntlv = (const float*)d_in[24];
    const float* ntlb = (const float*)d_in[25];
    const float* ntlu = (const float*)d_in[26];
    const float* bn2g = (const float*)d_in[27];
    const float* bn2b = (const float*)d_in[28];
    float* out = (float*)d_out;
    char* ws = (char*)d_ws;

    float* x_seq = (float*)(ws + 0);
    float* pre = (float*)(ws + 2097152);
    unsigned short* tmp = (unsigned short*)(ws + 0);
    size_t off = 33554432;
    unsigned short* h_out = (unsigned short*)(ws + off); off += 1048576;
    float* hsumT = (float*)(ws + off); off += 262144;
    float* hd_bn = (float*)(ws + off); off += 131072;
    float* tl_bn = (float*)(ws + off); off += 131072;
    unsigned short* tl_bf = (unsigned short*)(ws + off); off += 65536;
    float* lsrc = (float*)(ws + off); off += 524288;
    float* ldst = (float*)(ws + off); off += 524288;
    float* pre2 = (float*)(ws + off); off += 4194304;
    float2* part2 = (float2*)(ws + off); off += 32768;
    float* part = (float*)(ws + off); off += 8192;

    k_embed<<<32, 256, 0, stream>>>(seq, p2g, emb, x_seq);
    k_gemm_in<<<dim3(8, 64), 512, 0, stream>>>(x_seq, wih_f, wih_b, bih_f, bhh_f, bih_b, bhh_b, pre);
    k_lstm_m<<<2, 1024, 0, stream>>>(pre, whh_f, whh_b, h_out);
    k_gather<<<256, 256, 0, stream>>>(idx, p2g, h_out, hsumT);
    k_proj_bn<<<dim3(2, 128), 256, 0, stream>>>(hsumT, lsw, lsb, ldw, ldb,
                                                bn_sg, bn_sb, bn_dg, bn_db, hd_bn, tl_bn, tl_bf);
    k_ntl_A<<<512, 256, 0, stream>>>(hd_bn, tl_bn, ntlw, ntlv, tmp, lsrc, ldst);
    k_ntl_B<<<dim3(8, 512), 64, 0, stream>>>(tmp, tl_bf, lsrc, ldst, ntlb, pre2, part2);
    k_final<<<dim3(8, 16), 256, 0, stream>>>(pre2, part2, bn2g, bn2b, ntlu, mask, out, part);
    k_loss_fin<<<1, 64, 0, stream>>>(part, out);
}

// Round 13
// 170.445 us; speedup vs baseline: 1.6116x; 1.3857x over previous
//
#include <hip/hip_runtime.h>
#include <math.h>

namespace {

constexpr int cB = 32, cL = 128, cG = 64, cD = 256;
constexpr int cHD = 128, cH = 256;
constexpr int cN = 8, cK = 4;
constexpr int cNI = 128, cRH = 512;
constexpr int cE = 2048;
constexpr float cEPS = 1e-5f;

typedef __bf16 bf16x8 __attribute__((ext_vector_type(8)));
typedef float f32x4 __attribute__((ext_vector_type(4)));

__device__ __forceinline__ f32x4 mfma16(bf16x8 a, bf16x8 b, f32x4 c) {
    return __builtin_amdgcn_mfma_f32_16x16x32_bf16(a, b, c, 0, 0, 0);
}

__device__ __forceinline__ float bf2f(unsigned short u) {
    unsigned int x = ((unsigned int)u) << 16;
    return __uint_as_float(x);
}
__device__ __forceinline__ unsigned short f2bf(float f) {
    unsigned int x = __float_as_uint(f);
    unsigned int r = (x + 0x7fffu + ((x >> 16) & 1u)) >> 16;  // RNE
    return (unsigned short)r;
}
// unpack a u32 holding 2 bf16 (lo = elem k, hi = elem k+1)
__device__ __forceinline__ void bfp(unsigned int u, float& lo, float& hi) {
    lo = __uint_as_float(u << 16);
    hi = __uint_as_float(u & 0xffff0000u);
}
__device__ __forceinline__ float frcp(float x) { return __builtin_amdgcn_rcpf(x); }
__device__ __forceinline__ float fsig(float x) { return frcp(1.f + __expf(-x)); }
__device__ __forceinline__ float ftanh(float x) { return 1.f - 2.f * frcp(__expf(2.f * x) + 1.f); }
__device__ __forceinline__ float nls(float x) {
    return (x >= 0.f) ? log1pf(expf(-x)) : (log1pf(expf(x)) - x);
}
__device__ __forceinline__ bf16x8 cvt8(const float* __restrict__ p) {
    float4 a = *(const float4*)p, b = *(const float4*)(p + 4);
    bf16x8 v;
    v[0] = (__bf16)a.x; v[1] = (__bf16)a.y; v[2] = (__bf16)a.z; v[3] = (__bf16)a.w;
    v[4] = (__bf16)b.x; v[5] = (__bf16)b.y; v[6] = (__bf16)b.z; v[7] = (__bf16)b.w;
    return v;
}

// lgkm-only barrier: LDS ping-pong needs lgkmcnt ordering, NOT a vmcnt(0) drain.
__device__ __forceinline__ void bar_lgkm() {
    asm volatile("s_waitcnt lgkmcnt(0)\n\ts_barrier" ::: "memory");
}

// ---------------------------------------------------------------------------
// 1) token embedding + scatter_sum (verified).
__global__ __launch_bounds__(256) void k_embed(
    const int* __restrict__ seq, const int* __restrict__ p2g,
    const float* __restrict__ emb, float* __restrict__ x_seq) {
    __shared__ float xl[cG * cD];
    __shared__ int toks[cL], grps[cL];
    int b = blockIdx.x, t = threadIdx.x;
    if (t < 128) toks[t] = seq[b * cL + t];
    else grps[t - 128] = p2g[b * cL + (t - 128)];
    for (int g = 0; g < cG; ++g) xl[g * cD + t] = 0.f;
    __syncthreads();
    for (int l = 0; l < cL; l += 4) {
        float v0 = emb[(size_t)toks[l + 0] * cD + t];
        float v1 = emb[(size_t)toks[l + 1] * cD + t];
        float v2 = emb[(size_t)toks[l + 2] * cD + t];
        float v3 = emb[(size_t)toks[l + 3] * cD + t];
        xl[grps[l + 0] * cD + t] += v0;
        xl[grps[l + 1] * cD + t] += v1;
        xl[grps[l + 2] * cD + t] += v2;
        xl[grps[l + 3] * cD + t] += v3;
    }
    for (int g = 0; g < cG; ++g)
        x_seq[(g * cB + b) * cD + t] = xl[g * cD + t];
}

// ---------------------------------------------------------------------------
// 2) LSTM input GEMM via MFMA (verified).
__global__ __launch_bounds__(512) void k_gemm_in(
    const float* __restrict__ x_seq,
    const float* __restrict__ wih_f, const float* __restrict__ wih_b,
    const float* __restrict__ bih_f, const float* __restrict__ bhh_f,
    const float* __restrict__ bih_b, const float* __restrict__ bhh_b,
    float* __restrict__ pre) {
    int ns = blockIdx.x, g = blockIdx.y;
    int t = threadIdx.x;
    int w = t >> 6, l = t & 63, lc = l & 15, lk = l >> 4;
    int gn = ns * 128 + w * 16 + lc;
    const float* wrow = (gn < 512) ? (wih_f + (size_t)gn * cD)
                                   : (wih_b + (size_t)(gn - 512) * cD);
    const float* xb0 = x_seq + ((size_t)g * 32 + lc) * cD;
    const float* xb1 = x_seq + ((size_t)g * 32 + 16 + lc) * cD;
    f32x4 acc0 = {0.f, 0.f, 0.f, 0.f}, acc1 = {0.f, 0.f, 0.f, 0.f};
#pragma unroll
    for (int kf = 0; kf < 8; ++kf) {
        int ko = kf * 32 + lk * 8;
        bf16x8 a = cvt8(wrow + ko);
        bf16x8 b0 = cvt8(xb0 + ko);
        bf16x8 b1 = cvt8(xb1 + ko);
        acc0 = mfma16(a, b0, acc0);
        acc1 = mfma16(a, b1, acc1);
    }
    int nb = ns * 128 + w * 16 + lk * 4;
    float4 bv;
    if (nb < 512) {
        float4 u = *(const float4*)(bih_f + nb);
        float4 v = *(const float4*)(bhh_f + nb);
        bv = make_float4(u.x + v.x, u.y + v.y, u.z + v.z, u.w + v.w);
    } else {
        float4 u = *(const float4*)(bih_b + nb - 512);
        float4 v = *(const float4*)(bhh_b + nb - 512);
        bv = make_float4(u.x + v.x, u.y + v.y, u.z + v.z, u.w + v.w);
    }
    size_t base = ((size_t)g * 256 + (nb >> 2)) * 32;
    *(float4*)(pre + (base + lc) * 4) =
        make_float4(acc0[0] + bv.x, acc0[1] + bv.y, acc0[2] + bv.z, acc0[3] + bv.w);
    *(float4*)(pre + (base + 16 + lc) * 4) =
        make_float4(acc1[0] + bv.x, acc1[1] + bv.y, acc1[2] + bv.z, acc1[3] + bv.w);
}

// ---------------------------------------------------------------------------
// 3) MFMA LSTM — round-8 proven config: 4 blocks = (dir, bhalf); 512 thr =
//    8 waves (2/SIMD); VGPR 76, no spill; 59.6us measured.
//    (Rounds 9-12 showed: 512-thr waves cap at 128 VGPR, 1024-thr at 64,
//    launch_bounds can't raise them -> dir-interleave / 16-wave variants all
//    spill. This is the optimum for this toolchain.)
__device__ __forceinline__ void lstm_step(
    f32x4 (&acc)[4], float (&cst)[4], const bf16x8 (&wf)[4][4],
    const unsigned short* __restrict__ hr, unsigned short* __restrict__ hw,
    const int (&rdo)[4], int wro,
    const float* __restrict__ preb, int gpre, bool dopre,
    unsigned short* __restrict__ hob, int g) {
    bf16x8 hf[4];
#pragma unroll
    for (int kf = 0; kf < 4; ++kf)
        hf[kf] = *(const bf16x8*)((const char*)hr + rdo[kf]);
#pragma unroll
    for (int kf = 0; kf < 4; ++kf)
#pragma unroll
        for (int q = 0; q < 4; ++q)
            acc[q] = mfma16(wf[q][kf], hf[kf], acc[q]);
    float hv[4];
#pragma unroll
    for (int r = 0; r < 4; ++r) {
        float ig = fsig(acc[0][r]);
        float fg = fsig(acc[1][r]);
        float gg = ftanh(acc[2][r]);
        float og = fsig(acc[3][r]);
        float cv = fg * cst[r] + ig * gg;
        cst[r] = cv;
        hv[r] = og * ftanh(cv);
    }
    if (dopre) {
#pragma unroll
        for (int q = 0; q < 4; ++q)
            acc[q] = *(const f32x4*)(preb + (size_t)gpre * 32768 + q * 4096);
    }
    unsigned int p0 = (unsigned int)f2bf(hv[0]) | ((unsigned int)f2bf(hv[1]) << 16);
    unsigned int p1 = (unsigned int)f2bf(hv[2]) | ((unsigned int)f2bf(hv[3]) << 16);
    *(uint2*)((char*)hw + wro) = make_uint2(p0, p1);
    *(uint2*)(hob + (size_t)g * 8192) = make_uint2(p0, p1);
    bar_lgkm();
}

__global__ __launch_bounds__(512, 2) void k_lstm_m(
    const float* __restrict__ pre,
    const float* __restrict__ whh_f, const float* __restrict__ whh_b,
    unsigned short* __restrict__ h_out) {
    __shared__ __align__(16) unsigned short hl[2][2048];  // [buf][b(16) x h(128)] bf16
    int t = threadIdx.x;
    int w = t >> 6, l = t & 63, lc = l & 15, lk = l >> 4;
    int dir = blockIdx.x >> 1, bg = (blockIdx.x & 1) * 16;
    const float* whh = dir ? whh_b : whh_f;
    bf16x8 wf[4][4];
#pragma unroll
    for (int q = 0; q < 4; ++q) {
        int n = q * 128 + w * 16 + lc;
#pragma unroll
        for (int kf = 0; kf < 4; ++kf)
            wf[q][kf] = cvt8(whh + (size_t)n * 128 + kf * 32 + lk * 8);
    }
    *(uint2*)&hl[1][t * 4] = make_uint2(0u, 0u);
    const float* preb = pre + ((size_t)(dir * 128 + w * 4 + lk) * 32 + (bg + lc)) * 4;
    unsigned short* hob = h_out + ((size_t)(dir * 32 + bg + lc) * 128 + w * 16 + lk * 4);
    // full 4-bit XOR swizzle: physical = logical ^ (lc<<4)
    int rdo[4];
#pragma unroll
    for (int kf = 0; kf < 4; ++kf)
        rdo[kf] = (lc * 256 + kf * 64 + lk * 16) ^ (lc << 4);
    int wro = (lc * 256 + w * 32 + lk * 8) ^ (lc << 4);
    f32x4 accA[4], accB[4];
    float cst[4] = {0.f, 0.f, 0.f, 0.f};
    int g0 = dir ? 63 : 0;
    int sgn = dir ? -1 : 1;
#pragma unroll
    for (int q = 0; q < 4; ++q) accA[q] = *(const f32x4*)(preb + (size_t)g0 * 32768 + q * 4096);
#pragma unroll
    for (int q = 0; q < 4; ++q) accB[q] = *(const f32x4*)(preb + (size_t)(g0 + sgn) * 32768 + q * 4096);
    bar_lgkm();
    for (int s = 0; s < 64; s += 2) {
        int ga = g0 + sgn * s;
        lstm_step(accA, cst, wf, hl[1], hl[0], rdo, wro, preb, ga + 2 * sgn, s < 62, hob, ga);
        lstm_step(accB, cst, wf, hl[0], hl[1], rdo, wro, preb, ga + 3 * sgn, s < 61, hob, ga + sgn);
    }
}

// ---------------------------------------------------------------------------
// 4) gather(+sum over K) -> transposed hsumT[c][n] (verified).
__global__ __launch_bounds__(256) void k_gather(
    const int* __restrict__ idx, const int* __restrict__ p2g,
    const unsigned short* __restrict__ h_out, float* __restrict__ hsumT) {
    int bn = blockIdx.x;
    int b = bn >> 3;
    int t = threadIdx.x;
    int dirq = t >> 7, hh = t & 127;
    int l0 = idx[bn * cK + 0], l1 = idx[bn * cK + 1];
    int l2 = idx[bn * cK + 2], l3 = idx[bn * cK + 3];
    int g0 = p2g[b * cL + l0], g1 = p2g[b * cL + l1];
    int g2 = p2g[b * cL + l2], g3 = p2g[b * cL + l3];
    size_t ro = (size_t)(dirq * 32 + b) * 128 + hh;
    float a = bf2f(h_out[(size_t)g0 * 8192 + ro]) + bf2f(h_out[(size_t)g1 * 8192 + ro]) +
              bf2f(h_out[(size_t)g2 * 8192 + ro]) + bf2f(h_out[(size_t)g3 * 8192 + ro]);
    hsumT[(size_t)t * 256 + bn] = a;
}

// ---------------------------------------------------------------------------
// 5) fused projection + BatchNorm; dst side also emits bf16 copy for ntl_B.
__global__ __launch_bounds__(256) void k_proj_bn(
    const float* __restrict__ hsumT,
    const float* __restrict__ w_src, const float* __restrict__ b_src,
    const float* __restrict__ w_dst, const float* __restrict__ b_dst,
    const float* __restrict__ g_src, const float* __restrict__ bb_src,
    const float* __restrict__ g_dst, const float* __restrict__ bb_dst,
    float* __restrict__ hd_bn, float* __restrict__ tl_bn,
    unsigned short* __restrict__ tl_bf) {
    int which = blockIdx.x, c = blockIdx.y, t = threadIdx.x;
    __shared__ float ws[256];
    __shared__ float ssum[256], ssq[256];
    ws[t] = (which ? w_dst : w_src)[(size_t)c * cH + t];
    __syncthreads();
    float acc = (which ? b_dst : b_src)[c];
#pragma unroll 8
    for (int k = 0; k < cH; ++k)
        acc += ws[k] * hsumT[(size_t)k * 256 + t];
    ssum[t] = acc;
    ssq[t] = acc * acc;
    __syncthreads();
    for (int o = 128; o > 0; o >>= 1) {
        if (t < o) { ssum[t] += ssum[t + o]; ssq[t] += ssq[t + o]; }
        __syncthreads();
    }
    float mean = ssum[0] * (1.f / 256.f);
    float var = ssq[0] * (1.f / 256.f) - mean * mean;
    float gam = which ? g_dst[c] : g_src[c];
    float bet = which ? bb_dst[c] : bb_src[c];
    float scale = gam * rsqrtf(var + cEPS);
    float val = (acc - mean) * scale + bet;
    (which ? tl_bn : hd_bn)[(size_t)t * cNI + c] = val;
    if (which) tl_bf[(size_t)t * cNI + c] = f2bf(val);
}

// ---------------------------------------------------------------------------
// 6) MFMA NTL-A + fused lin (verified, unchanged).
__global__ __launch_bounds__(256, 2) void k_ntl_A(
    const float* __restrict__ hd_bn, const float* __restrict__ tl_bn,
    const float* __restrict__ ntl_w, const float* __restrict__ ntl_v,
    unsigned short* __restrict__ tmp,
    float* __restrict__ lsrc, float* __restrict__ ldst) {
    __shared__ __align__(16) unsigned short wl[128 * 128];
    __shared__ float vsh[256];
    int rh = blockIdx.x, t = threadIdx.x;
    int w = t >> 6, l = t & 63, lc = l & 15, lk = l >> 4;
    vsh[t] = ntl_v[(size_t)rh * 256 + t];
    {
        const float* wbase = ntl_w + (size_t)rh * 16384;
        int k = t >> 1, c0 = (t & 1) * 64;
        int sw = ((k >> 3) & 3) << 4;
#pragma unroll
        for (int u = 0; u < 8; ++u) {
            bf16x8 v = cvt8(wbase + k * 128 + c0 + u * 8);
            *(bf16x8*)((char*)wl + ((k * 256 + (c0 + u * 8) * 2) ^ sw)) = v;
        }
    }
    __syncthreads();
    {
        const float* hr = hd_bn + (size_t)t * cNI;
        const float* tr = tl_bn + (size_t)t * cNI;
        float a1 = 0.f, a2 = 0.f;
#pragma unroll 8
        for (int i = 0; i < cNI; i += 4) {
            float4 h4 = *(const float4*)(hr + i);
            float4 t4 = *(const float4*)(tr + i);
            a1 += h4.x * vsh[i] + h4.y * vsh[i + 1] + h4.z * vsh[i + 2] + h4.w * vsh[i + 3];
            a2 += t4.x * vsh[128 + i] + t4.y * vsh[128 + i + 1] + t4.z * vsh[128 + i + 2] + t4.w * vsh[128 + i + 3];
        }
        lsrc[(size_t)rh * 256 + t] = a1;
        ldst[(size_t)rh * 256 + t] = a2;
    }
    f32x4 acc[4][8] = {};
#pragma unroll
    for (int kf = 0; kf < 4; ++kf) {
        bf16x8 af[4];
#pragma unroll
        for (int mt = 0; mt < 4; ++mt) {
            int m = w * 64 + mt * 16 + lc;
            af[mt] = cvt8(hd_bn + (size_t)m * 128 + kf * 32 + lk * 8);
        }
#pragma unroll
        for (int nt = 0; nt < 8; ++nt) {
            int kb = (kf * 32 + lk * 8) * 256;
            int jb = (nt * 16 + lc) * 2;
            bf16x8 bv = *(const bf16x8*)((char*)wl + ((kb + jb) ^ (lk << 4)));
#pragma unroll
            for (int mt = 0; mt < 4; ++mt) acc[mt][nt] = mfma16(af[mt], bv, acc[mt][nt]);
        }
    }
#pragma unroll
    for (int mt = 0; mt < 4; ++mt) {
#pragma unroll
        for (int nt = 0; nt < 8; ++nt) {
            unsigned int lo = (unsigned int)f2bf(acc[mt][nt][0]) | ((unsigned int)f2bf(acc[mt][nt][1]) << 16);
            unsigned int hi = (unsigned int)f2bf(acc[mt][nt][2]) | ((unsigned int)f2bf(acc[mt][nt][3]) << 16);
            size_t off = (size_t)rh * 32768 + (size_t)((((w * 4 + mt) * 8 + nt) * 64 + l) * 4);
            *(uint2*)(tmp + off) = make_uint2(lo, hi);
        }
    }
}

// ---------------------------------------------------------------------------
// 7) bilinear + linear + bias -> pre2[rh][e], + BN partials (round-12 bf16 v2).
__global__ __launch_bounds__(64) void k_ntl_B(
    const unsigned short* __restrict__ tmp, const unsigned short* __restrict__ tl_bf,
    const float* __restrict__ lsrc, const float* __restrict__ ldst,
    const float* __restrict__ ntl_b, float* __restrict__ pre2,
    float2* __restrict__ part2) {
    int bgid = blockIdx.x;
    int rh = blockIdx.y;
    int t = threadIdx.x;
    int n0 = bgid * 32;
    __shared__ unsigned short tm[32][136];
    __shared__ unsigned short tl[32][136];
    {
        const uint4* src = (const uint4*)(tmp + (size_t)rh * 32768 +
                                          (size_t)(bgid >> 1) * 8192 + (size_t)(bgid & 1) * 4096);
#pragma unroll
        for (int rep = 0; rep < 8; ++rep) {
            int q = t + rep * 64;
            uint4 uv = src[q];
            unsigned int wds[4] = {uv.x, uv.y, uv.z, uv.w};
            int e0 = q * 8;
#pragma unroll
            for (int ui = 0; ui < 4; ++ui) {
                int e = e0 + ui * 2;
                int mt_l = e >> 11;
                int nt = (e >> 8) & 7;
                int ln = (e >> 2) & 63;
                int r = e & 3;
                int m = mt_l * 16 + (ln >> 4) * 4 + r;
                int j = nt * 16 + (ln & 15);
                tm[m][j] = (unsigned short)(wds[ui] & 0xffffu);
                tm[m + 1][j] = (unsigned short)(wds[ui] >> 16);
            }
        }
        int row = t >> 1, c0 = (t & 1) * 64;
        const uint4* fsrc = (const uint4*)(tl_bf + (size_t)(n0 + row) * cNI + c0);
#pragma unroll
        for (int u = 0; u < 8; ++u) {
            uint4 v = fsrc[u];
            *(uint4*)&tl[row][c0 + u * 8] = v;
        }
    }
    __syncthreads();
    int b_l = t >> 4, i2 = (t >> 2) & 3, j2 = t & 3;
    const unsigned short* ta0 = &tm[b_l * 8 + i2][0];
    const unsigned short* ta1 = &tm[b_l * 8 + i2 + 4][0];
    const unsigned short* tb0 = &tl[b_l * 8 + j2][0];
    const unsigned short* tb1 = &tl[b_l * 8 + j2 + 4][0];
    float s00 = 0.f, s01 = 0.f, s10 = 0.f, s11 = 0.f;
#pragma unroll 4
    for (int k4 = 0; k4 < 32; ++k4) {
        uint2 ua0 = *(const uint2*)&ta0[k4 * 4];
        uint2 ua1 = *(const uint2*)&ta1[k4 * 4];
        uint2 ub0 = *(const uint2*)&tb0[k4 * 4];
        uint2 ub1 = *(const uint2*)&tb1[k4 * 4];
        float a0l, a0h, a1l, a1h, b0l, b0h, b1l, b1h;
        bfp(ua0.x, a0l, a0h); bfp(ua1.x, a1l, a1h);
        bfp(ub0.x, b0l, b0h); bfp(ub1.x, b1l, b1h);
        s00 += a0l * b0l + a0h * b0h;
        s01 += a0l * b1l + a0h * b1h;
        s10 += a1l * b0l + a1h * b0h;
        s11 += a1l * b1l + a1h * b1h;
        bfp(ua0.y, a0l, a0h); bfp(ua1.y, a1l, a1h);
        bfp(ub0.y, b0l, b0h); bfp(ub1.y, b1l, b1h);
        s00 += a0l * b0l + a0h * b0h;
        s01 += a0l * b1l + a0h * b1h;
        s10 += a1l * b0l + a1h * b0h;
        s11 += a1l * b1l + a1h * b1h;
    }
    int bglob = bgid * 4 + b_l;
    float nb = ntl_b[rh];
    const float* ls = lsrc + (size_t)rh * 256 + bglob * 8;
    const float* ld = ldst + (size_t)rh * 256 + bglob * 8;
    float* pr = pre2 + (size_t)rh * cE + bgid * 256 + b_l * 64;
    float vs[4];
    vs[0] = s00 + ls[i2] + ld[j2] + nb;
    vs[1] = s01 + ls[i2] + ld[j2 + 4] + nb;
    vs[2] = s10 + ls[i2 + 4] + ld[j2] + nb;
    vs[3] = s11 + ls[i2 + 4] + ld[j2 + 4] + nb;
    pr[i2 * 8 + j2] = vs[0];
    pr[i2 * 8 + j2 + 4] = vs[1];
    pr[(i2 + 4) * 8 + j2] = vs[2];
    pr[(i2 + 4) * 8 + j2 + 4] = vs[3];
    float sm = vs[0] + vs[1] + vs[2] + vs[3];
    float sq = vs[0] * vs[0] + vs[1] * vs[1] + vs[2] * vs[2] + vs[3] * vs[3];
#pragma unroll
    for (int o = 32; o > 0; o >>= 1) {
        sm += __shfl_down(sm, o);
        sq += __shfl_down(sq, o);
    }
    if (t == 0) part2[(size_t)rh * 8 + bgid] = make_float2(sm, sq);
}

// ---------------------------------------------------------------------------
// 8) logit + in-kernel BN2 + fused loss partials (verified).
__global__ __launch_bounds__(256) void k_final(
    const float* __restrict__ pre2, const float2* __restrict__ part2,
    const float* __restrict__ g2, const float* __restrict__ b2,
    const float* __restrict__ ntl_u, const int* __restrict__ mask,
    float* __restrict__ out, float* __restrict__ part) {
    int r = blockIdx.y, et = blockIdx.x;
    int t = threadIdx.x;
    __shared__ float sc[32], sh[32];
    {
        int rh_l = t >> 3, slot = t & 7;
        int rh = r * 32 + rh_l;
        float2 pp = part2[(size_t)rh * 8 + slot];
        float S = pp.x, Q = pp.y;
        S += __shfl_xor(S, 1); Q += __shfl_xor(Q, 1);
        S += __shfl_xor(S, 2); Q += __shfl_xor(Q, 2);
        S += __shfl_xor(S, 4); Q += __shfl_xor(Q, 4);
        if (slot == 0) {
            float mean = S * (1.f / 2048.f);
            float var = Q * (1.f / 2048.f) - mean * mean;
            float scv = g2[rh] * rsqrtf(var + cEPS);
            sc[rh_l] = scv;
            sh[rh_l] = b2[rh] - mean * scv;
        }
    }
    __syncthreads();
    int e = et * 256 + t;
    float a = 0.f;
#pragma unroll
    for (int h = 0; h < 32; ++h) {
        int rh = r * 32 + h;
        float p = pre2[(size_t)rh * cE + e];
        a += ntl_u[rh] * ftanh(fmaf(p, sc[h], sh[h]));
    }
    out[(size_t)e * 16 + r] = a;
    int m = mask[(size_t)e * 16 + r];
    bool mb = (m != 0);
    bool eq = ((a > 0.f) == mb);
    float nll = mb ? nls(a) : -logf(1.f / (1.f + expf(a)) + 1e-5f);
    float corr = eq ? 1.f : 0.f;
    unsigned long long bal = __ballot(eq);
    float em = (bal == ~0ull) ? 1.f : 0.f;
#pragma unroll
    for (int o = 32; o > 0; o >>= 1) {
        nll += __shfl_down(nll, o);
        corr += __shfl_down(corr, o);
    }
    if ((t & 63) == 0) {
        int bg = et * 4 + (t >> 6);
        float* p = part + ((size_t)bg * 16 + r) * 4;
        p[0] = nll; p[1] = corr; p[2] = em;
    }
}

// ---------------------------------------------------------------------------
// 9) final loss reduction
__global__ void k_loss_fin(const float* __restrict__ part, float* __restrict__ out) {
    int t = threadIdx.x;
    float nll = 0.f, corr = 0.f, em = 0.f;
    if (t < 32) {
        em = 1.f;
        for (int r = 0; r < 16; ++r) {
            const float* p = part + ((size_t)t * 16 + r) * 4;
            nll += p[0]; corr += p[1]; em = fminf(em, p[2]);
        }
    }
#pragma unroll
    for (int o = 32; o > 0; o >>= 1) {
        nll += __shfl_down(nll, o);
        corr += __shfl_down(corr, o);
        em += __shfl_down(em, o);
    }
    if (t == 0) {
        out[32768] = nll / 32.f;
        out[32769] = corr / 32768.f;
        out[32770] = em / 32.f;
    }
}

}  // namespace

extern "C" void kernel_launch(void* const* d_in, const int* in_sizes, int n_in,
                              void* d_out, int out_size, void* d_ws, size_t ws_size,
                              hipStream_t stream) {
    (void)in_sizes; (void)n_in; (void)out_size; (void)ws_size;
    const int* seq = (const int*)d_in[0];
    const int* p2g = (const int*)d_in[1];
    const int* idx = (const int*)d_in[2];
    const int* mask = (const int*)d_in[5];
    const float* emb = (const float*)d_in[6];
    const float* wih_f = (const float*)d_in[7];
    const float* whh_f = (const float*)d_in[8];
    const float* bih_f = (const float*)d_in[9];
    const float* bhh_f = (const float*)d_in[10];
    const float* wih_b = (const float*)d_in[11];
    const float* whh_b = (const float*)d_in[12];
    const float* bih_b = (const float*)d_in[13];
    const float* bhh_b = (const float*)d_in[14];
    const float* lsw = (const float*)d_in[15];
    const float* lsb = (const float*)d_in[16];
    const float* ldw = (const float*)d_in[17];
    const float* ldb = (const float*)d_in[18];
    const float* bn_sg = (const float*)d_in[19];
    const float* bn_sb = (const float*)d_in[20];
    const float* bn_dg = (const float*)d_in[21];
    const float* bn_db = (const float*)d_in[22];
    const float* ntlw = (const float*)d_in[23];
    const float* ntlv = (const float*)d_in[24];
    const float* ntlb = (const float*)d_in[25];
    const float* ntlu = (const float*)d_in[26];
    const float* bn2g = (const float*)d_in[27];
    const float* bn2b = (const float*)d_in[28];
    float* out = (float*)d_out;
    char* ws = (char*)d_ws;

    float* x_seq = (float*)(ws + 0);
    float* pre = (float*)(ws + 2097152);
    unsigned short* tmp = (unsigned short*)(ws + 0);
    size_t off = 33554432;
    unsigned short* h_out = (unsigned short*)(ws + off); off += 1048576;
    float* hsumT = (float*)(ws + off); off += 262144;
    float* hd_bn = (float*)(ws + off); off += 131072;
    float* tl_bn = (float*)(ws + off); off += 131072;
    unsigned short* tl_bf = (unsigned short*)(ws + off); off += 65536;
    float* lsrc = (float*)(ws + off); off += 524288;
    float* ldst = (float*)(ws + off); off += 524288;
    float* pre2 = (float*)(ws + off); off += 4194304;
    float2* part2 = (float2*)(ws + off); off += 32768;
    float* part = (float*)(ws + off); off += 8192;

    k_embed<<<32, 256, 0, stream>>>(seq, p2g, emb, x_seq);
    k_gemm_in<<<dim3(8, 64), 512, 0, stream>>>(x_seq, wih_f, wih_b, bih_f, bhh_f, bih_b, bhh_b, pre);
    k_lstm_m<<<4, 512, 0, stream>>>(pre, whh_f, whh_b, h_out);
    k_gather<<<256, 256, 0, stream>>>(idx, p2g, h_out, hsumT);
    k_proj_bn<<<dim3(2, 128), 256, 0, stream>>>(hsumT, lsw, lsb, ldw, ldb,
                                                bn_sg, bn_sb, bn_dg, bn_db, hd_bn, tl_bn, tl_bf);
    k_ntl_A<<<512, 256, 0, stream>>>(hd_bn, tl_bn, ntlw, ntlv, tmp, lsrc, ldst);
    k_ntl_B<<<dim3(8, 512), 64, 0, stream>>>(tmp, tl_bf, lsrc, ldst, ntlb, pre2, part2);
    k_final<<<dim3(8, 16), 256, 0, stream>>>(pre2, part2, bn2g, bn2b, ntlu, mask, out, part);
    k_loss_fin<<<1, 64, 0, stream>>>(part, out);
}

// Round 14
// 156.439 us; speedup vs baseline: 1.7559x; 1.0895x over previous
//
#include <hip/hip_runtime.h>
#include <math.h>

namespace {

constexpr int cB = 32, cL = 128, cG = 64, cD = 256;
constexpr int cHD = 128, cH = 256;
constexpr int cN = 8, cK = 4;
constexpr int cNI = 128, cRH = 512;
constexpr int cE = 2048;
constexpr float cEPS = 1e-5f;

typedef __bf16 bf16x8 __attribute__((ext_vector_type(8)));
typedef float f32x4 __attribute__((ext_vector_type(4)));

__device__ __forceinline__ f32x4 mfma16(bf16x8 a, bf16x8 b, f32x4 c) {
    return __builtin_amdgcn_mfma_f32_16x16x32_bf16(a, b, c, 0, 0, 0);
}

__device__ __forceinline__ float bf2f(unsigned short u) {
    unsigned int x = ((unsigned int)u) << 16;
    return __uint_as_float(x);
}
__device__ __forceinline__ unsigned short f2bf(float f) {
    unsigned int x = __float_as_uint(f);
    unsigned int r = (x + 0x7fffu + ((x >> 16) & 1u)) >> 16;  // RNE
    return (unsigned short)r;
}
__device__ __forceinline__ float frcp(float x) { return __builtin_amdgcn_rcpf(x); }
__device__ __forceinline__ float fsig(float x) { return frcp(1.f + __expf(-x)); }
__device__ __forceinline__ float ftanh(float x) { return 1.f - 2.f * frcp(__expf(2.f * x) + 1.f); }
__device__ __forceinline__ float nls(float x) {
    return (x >= 0.f) ? log1pf(expf(-x)) : (log1pf(expf(x)) - x);
}
__device__ __forceinline__ bf16x8 cvt8(const float* __restrict__ p) {
    float4 a = *(const float4*)p, b = *(const float4*)(p + 4);
    bf16x8 v;
    v[0] = (__bf16)a.x; v[1] = (__bf16)a.y; v[2] = (__bf16)a.z; v[3] = (__bf16)a.w;
    v[4] = (__bf16)b.x; v[5] = (__bf16)b.y; v[6] = (__bf16)b.z; v[7] = (__bf16)b.w;
    return v;
}

// lgkm-only barrier: LDS ping-pong needs lgkmcnt ordering, NOT a vmcnt(0) drain.
__device__ __forceinline__ void bar_lgkm() {
    asm volatile("s_waitcnt lgkmcnt(0)\n\ts_barrier" ::: "memory");
}

// ---------------------------------------------------------------------------
// 1) token embedding + scatter_sum (verified).
__global__ __launch_bounds__(256) void k_embed(
    const int* __restrict__ seq, const int* __restrict__ p2g,
    const float* __restrict__ emb, float* __restrict__ x_seq) {
    __shared__ float xl[cG * cD];
    __shared__ int toks[cL], grps[cL];
    int b = blockIdx.x, t = threadIdx.x;
    if (t < 128) toks[t] = seq[b * cL + t];
    else grps[t - 128] = p2g[b * cL + (t - 128)];
    for (int g = 0; g < cG; ++g) xl[g * cD + t] = 0.f;
    __syncthreads();
    for (int l = 0; l < cL; l += 4) {
        float v0 = emb[(size_t)toks[l + 0] * cD + t];
        float v1 = emb[(size_t)toks[l + 1] * cD + t];
        float v2 = emb[(size_t)toks[l + 2] * cD + t];
        float v3 = emb[(size_t)toks[l + 3] * cD + t];
        xl[grps[l + 0] * cD + t] += v0;
        xl[grps[l + 1] * cD + t] += v1;
        xl[grps[l + 2] * cD + t] += v2;
        xl[grps[l + 3] * cD + t] += v3;
    }
    for (int g = 0; g < cG; ++g)
        x_seq[(g * cB + b) * cD + t] = xl[g * cD + t];
}

// ---------------------------------------------------------------------------
// 2) LSTM input GEMM via MFMA (verified).
__global__ __launch_bounds__(512) void k_gemm_in(
    const float* __restrict__ x_seq,
    const float* __restrict__ wih_f, const float* __restrict__ wih_b,
    const float* __restrict__ bih_f, const float* __restrict__ bhh_f,
    const float* __restrict__ bih_b, const float* __restrict__ bhh_b,
    float* __restrict__ pre) {
    int ns = blockIdx.x, g = blockIdx.y;
    int t = threadIdx.x;
    int w = t >> 6, l = t & 63, lc = l & 15, lk = l >> 4;
    int gn = ns * 128 + w * 16 + lc;
    const float* wrow = (gn < 512) ? (wih_f + (size_t)gn * cD)
                                   : (wih_b + (size_t)(gn - 512) * cD);
    const float* xb0 = x_seq + ((size_t)g * 32 + lc) * cD;
    const float* xb1 = x_seq + ((size_t)g * 32 + 16 + lc) * cD;
    f32x4 acc0 = {0.f, 0.f, 0.f, 0.f}, acc1 = {0.f, 0.f, 0.f, 0.f};
#pragma unroll
    for (int kf = 0; kf < 8; ++kf) {
        int ko = kf * 32 + lk * 8;
        bf16x8 a = cvt8(wrow + ko);
        bf16x8 b0 = cvt8(xb0 + ko);
        bf16x8 b1 = cvt8(xb1 + ko);
        acc0 = mfma16(a, b0, acc0);
        acc1 = mfma16(a, b1, acc1);
    }
    int nb = ns * 128 + w * 16 + lk * 4;
    float4 bv;
    if (nb < 512) {
        float4 u = *(const float4*)(bih_f + nb);
        float4 v = *(const float4*)(bhh_f + nb);
        bv = make_float4(u.x + v.x, u.y + v.y, u.z + v.z, u.w + v.w);
    } else {
        float4 u = *(const float4*)(bih_b + nb - 512);
        float4 v = *(const float4*)(bhh_b + nb - 512);
        bv = make_float4(u.x + v.x, u.y + v.y, u.z + v.z, u.w + v.w);
    }
    size_t base = ((size_t)g * 256 + (nb >> 2)) * 32;
    *(float4*)(pre + (base + lc) * 4) =
        make_float4(acc0[0] + bv.x, acc0[1] + bv.y, acc0[2] + bv.z, acc0[3] + bv.w);
    *(float4*)(pre + (base + 16 + lc) * 4) =
        make_float4(acc1[0] + bv.x, acc1[1] + bv.y, acc1[2] + bv.z, acc1[3] + bv.w);
}

// ---------------------------------------------------------------------------
// 3) MFMA LSTM — round-8 proven config (59.6us, VGPR 76, no spill).
__device__ __forceinline__ void lstm_step(
    f32x4 (&acc)[4], float (&cst)[4], const bf16x8 (&wf)[4][4],
    const unsigned short* __restrict__ hr, unsigned short* __restrict__ hw,
    const int (&rdo)[4], int wro,
    const float* __restrict__ preb, int gpre, bool dopre,
    unsigned short* __restrict__ hob, int g) {
    bf16x8 hf[4];
#pragma unroll
    for (int kf = 0; kf < 4; ++kf)
        hf[kf] = *(const bf16x8*)((const char*)hr + rdo[kf]);
#pragma unroll
    for (int kf = 0; kf < 4; ++kf)
#pragma unroll
        for (int q = 0; q < 4; ++q)
            acc[q] = mfma16(wf[q][kf], hf[kf], acc[q]);
    float hv[4];
#pragma unroll
    for (int r = 0; r < 4; ++r) {
        float ig = fsig(acc[0][r]);
        float fg = fsig(acc[1][r]);
        float gg = ftanh(acc[2][r]);
        float og = fsig(acc[3][r]);
        float cv = fg * cst[r] + ig * gg;
        cst[r] = cv;
        hv[r] = og * ftanh(cv);
    }
    if (dopre) {
#pragma unroll
        for (int q = 0; q < 4; ++q)
            acc[q] = *(const f32x4*)(preb + (size_t)gpre * 32768 + q * 4096);
    }
    unsigned int p0 = (unsigned int)f2bf(hv[0]) | ((unsigned int)f2bf(hv[1]) << 16);
    unsigned int p1 = (unsigned int)f2bf(hv[2]) | ((unsigned int)f2bf(hv[3]) << 16);
    *(uint2*)((char*)hw + wro) = make_uint2(p0, p1);
    *(uint2*)(hob + (size_t)g * 8192) = make_uint2(p0, p1);
    bar_lgkm();
}

__global__ __launch_bounds__(512, 2) void k_lstm_m(
    const float* __restrict__ pre,
    const float* __restrict__ whh_f, const float* __restrict__ whh_b,
    unsigned short* __restrict__ h_out) {
    __shared__ __align__(16) unsigned short hl[2][2048];
    int t = threadIdx.x;
    int w = t >> 6, l = t & 63, lc = l & 15, lk = l >> 4;
    int dir = blockIdx.x >> 1, bg = (blockIdx.x & 1) * 16;
    const float* whh = dir ? whh_b : whh_f;
    bf16x8 wf[4][4];
#pragma unroll
    for (int q = 0; q < 4; ++q) {
        int n = q * 128 + w * 16 + lc;
#pragma unroll
        for (int kf = 0; kf < 4; ++kf)
            wf[q][kf] = cvt8(whh + (size_t)n * 128 + kf * 32 + lk * 8);
    }
    *(uint2*)&hl[1][t * 4] = make_uint2(0u, 0u);
    const float* preb = pre + ((size_t)(dir * 128 + w * 4 + lk) * 32 + (bg + lc)) * 4;
    unsigned short* hob = h_out + ((size_t)(dir * 32 + bg + lc) * 128 + w * 16 + lk * 4);
    int rdo[4];
#pragma unroll
    for (int kf = 0; kf < 4; ++kf)
        rdo[kf] = (lc * 256 + kf * 64 + lk * 16) ^ (lc << 4);
    int wro = (lc * 256 + w * 32 + lk * 8) ^ (lc << 4);
    f32x4 accA[4], accB[4];
    float cst[4] = {0.f, 0.f, 0.f, 0.f};
    int g0 = dir ? 63 : 0;
    int sgn = dir ? -1 : 1;
#pragma unroll
    for (int q = 0; q < 4; ++q) accA[q] = *(const f32x4*)(preb + (size_t)g0 * 32768 + q * 4096);
#pragma unroll
    for (int q = 0; q < 4; ++q) accB[q] = *(const f32x4*)(preb + (size_t)(g0 + sgn) * 32768 + q * 4096);
    bar_lgkm();
    for (int s = 0; s < 64; s += 2) {
        int ga = g0 + sgn * s;
        lstm_step(accA, cst, wf, hl[1], hl[0], rdo, wro, preb, ga + 2 * sgn, s < 62, hob, ga);
        lstm_step(accB, cst, wf, hl[0], hl[1], rdo, wro, preb, ga + 3 * sgn, s < 61, hob, ga + sgn);
    }
}

// ---------------------------------------------------------------------------
// 4) gather(+sum over K) -> transposed hsumT[c][n] (verified).
__global__ __launch_bounds__(256) void k_gather(
    const int* __restrict__ idx, const int* __restrict__ p2g,
    const unsigned short* __restrict__ h_out, float* __restrict__ hsumT) {
    int bn = blockIdx.x;
    int b = bn >> 3;
    int t = threadIdx.x;
    int dirq = t >> 7, hh = t & 127;
    int l0 = idx[bn * cK + 0], l1 = idx[bn * cK + 1];
    int l2 = idx[bn * cK + 2], l3 = idx[bn * cK + 3];
    int g0 = p2g[b * cL + l0], g1 = p2g[b * cL + l1];
    int g2 = p2g[b * cL + l2], g3 = p2g[b * cL + l3];
    size_t ro = (size_t)(dirq * 32 + b) * 128 + hh;
    float a = bf2f(h_out[(size_t)g0 * 8192 + ro]) + bf2f(h_out[(size_t)g1 * 8192 + ro]) +
              bf2f(h_out[(size_t)g2 * 8192 + ro]) + bf2f(h_out[(size_t)g3 * 8192 + ro]);
    hsumT[(size_t)t * 256 + bn] = a;
}

// ---------------------------------------------------------------------------
// 5) fused projection + BatchNorm; dst side also emits bf16 copy (verified).
__global__ __launch_bounds__(256) void k_proj_bn(
    const float* __restrict__ hsumT,
    const float* __restrict__ w_src, const float* __restrict__ b_src,
    const float* __restrict__ w_dst, const float* __restrict__ b_dst,
    const float* __restrict__ g_src, const float* __restrict__ bb_src,
    const float* __restrict__ g_dst, const float* __restrict__ bb_dst,
    float* __restrict__ hd_bn, float* __restrict__ tl_bn,
    unsigned short* __restrict__ tl_bf) {
    int which = blockIdx.x, c = blockIdx.y, t = threadIdx.x;
    __shared__ float ws[256];
    __shared__ float ssum[256], ssq[256];
    ws[t] = (which ? w_dst : w_src)[(size_t)c * cH + t];
    __syncthreads();
    float acc = (which ? b_dst : b_src)[c];
#pragma unroll 8
    for (int k = 0; k < cH; ++k)
        acc += ws[k] * hsumT[(size_t)k * 256 + t];
    ssum[t] = acc;
    ssq[t] = acc * acc;
    __syncthreads();
    for (int o = 128; o > 0; o >>= 1) {
        if (t < o) { ssum[t] += ssum[t + o]; ssq[t] += ssq[t + o]; }
        __syncthreads();
    }
    float mean = ssum[0] * (1.f / 256.f);
    float var = ssq[0] * (1.f / 256.f) - mean * mean;
    float gam = which ? g_dst[c] : g_src[c];
    float bet = which ? bb_dst[c] : bb_src[c];
    float scale = gam * rsqrtf(var + cEPS);
    float val = (acc - mean) * scale + bet;
    (which ? tl_bn : hd_bn)[(size_t)t * cNI + c] = val;
    if (which) tl_bf[(size_t)t * cNI + c] = f2bf(val);
}

// ---------------------------------------------------------------------------
// 6) FUSED NTL: per-rh block computes lin (LDS), T = hd@W (MFMA, regs), T->LDS
//    bf16, then P = T . tl^T via diagonal-tile MFMA with B-fragments streamed
//    from global tl_bf. Writes pre2 + single BN partial. No tmp buffer.
__global__ __launch_bounds__(256, 2) void k_ntl(
    const float* __restrict__ hd_bn, const float* __restrict__ tl_bn,
    const unsigned short* __restrict__ tl_bf,
    const float* __restrict__ ntl_w, const float* __restrict__ ntl_v,
    const float* __restrict__ ntl_b,
    float* __restrict__ pre2, float2* __restrict__ part2) {
    __shared__ __align__(16) unsigned short Tl[256 * 128];  // 64KB; first 32KB = W stage
    __shared__ float vsh[256];
    __shared__ float lsl[256], ldl[256];
    __shared__ float rs[8];
    int rh = blockIdx.x, t = threadIdx.x;
    int w = t >> 6, l = t & 63, lc = l & 15, lk = l >> 4;
    vsh[t] = ntl_v[(size_t)rh * 256 + t];
    // stage W (bf16, swizzled) into first 32KB of Tl
    unsigned short* wl = Tl;
    {
        const float* wbase = ntl_w + (size_t)rh * 16384;
        int k = t >> 1, c0 = (t & 1) * 64;
        int sw = ((k >> 3) & 3) << 4;
#pragma unroll
        for (int u = 0; u < 8; ++u) {
            bf16x8 v = cvt8(wbase + k * 128 + c0 + u * 8);
            *(bf16x8*)((char*)wl + ((k * 256 + (c0 + u * 8) * 2) ^ sw)) = v;
        }
    }
    __syncthreads();
    // lin part -> LDS only
    {
        const float* hr = hd_bn + (size_t)t * cNI;
        const float* tr = tl_bn + (size_t)t * cNI;
        float a1 = 0.f, a2 = 0.f;
#pragma unroll 8
        for (int i = 0; i < cNI; i += 4) {
            float4 h4 = *(const float4*)(hr + i);
            float4 t4 = *(const float4*)(tr + i);
            a1 += h4.x * vsh[i] + h4.y * vsh[i + 1] + h4.z * vsh[i + 2] + h4.w * vsh[i + 3];
            a2 += t4.x * vsh[128 + i] + t4.y * vsh[128 + i + 1] + t4.z * vsh[128 + i + 2] + t4.w * vsh[128 + i + 3];
        }
        lsl[t] = a1;
        ldl[t] = a2;
    }
    // phase 1: T = hd @ W  (rows m = node, cols j)
    f32x4 acc[4][8] = {};
#pragma unroll
    for (int kf = 0; kf < 4; ++kf) {
        bf16x8 af[4];
#pragma unroll
        for (int mt = 0; mt < 4; ++mt) {
            int m = w * 64 + mt * 16 + lc;
            af[mt] = cvt8(hd_bn + (size_t)m * 128 + kf * 32 + lk * 8);
        }
#pragma unroll
        for (int nt = 0; nt < 8; ++nt) {
            int kb = (kf * 32 + lk * 8) * 256;
            int jb = (nt * 16 + lc) * 2;
            bf16x8 bv = *(const bf16x8*)((char*)wl + ((kb + jb) ^ (lk << 4)));
#pragma unroll
            for (int mt = 0; mt < 4; ++mt) acc[mt][nt] = mfma16(af[mt], bv, acc[mt][nt]);
        }
    }
    __syncthreads();  // all W reads done; safe to overwrite with T
    // write T bf16 into Tl, swizzle ^((row&7)<<4)
#pragma unroll
    for (int mt = 0; mt < 4; ++mt) {
#pragma unroll
        for (int nt = 0; nt < 8; ++nt) {
#pragma unroll
            for (int r = 0; r < 4; ++r) {
                int row = w * 64 + mt * 16 + lk * 4 + r;
                int col = nt * 16 + lc;
                int byte = (row * 256 + col * 2) ^ ((row & 7) << 4);
                *(unsigned short*)((char*)Tl + byte) = f2bf(acc[mt][nt][r]);
            }
        }
    }
    __syncthreads();
    // phase 2: diagonal 16x16 tiles, P = T . tl^T ; wave w owns tiles w*4..w*4+3
    float nb = ntl_b[rh];
    float sm = 0.f, sq = 0.f;
#pragma unroll
    for (int p = 0; p < 4; ++p) {
        int ti = w * 4 + p;
        int arow = ti * 16 + lc;
        f32x4 d = {0.f, 0.f, 0.f, 0.f};
#pragma unroll
        for (int kf = 0; kf < 4; ++kf) {
            const char* ta = (const char*)Tl +
                ((arow * 256 + (kf * 32 + lk * 8) * 2) ^ ((arow & 7) << 4));
            bf16x8 a = *(const bf16x8*)ta;
            bf16x8 b = *(const bf16x8*)(tl_bf + (size_t)arow * 128 + kf * 32 + lk * 8);
            d = mfma16(a, b, d);
        }
        int jg = lc >> 3;
#pragma unroll
        for (int r = 0; r < 4; ++r) {
            int i = lk * 4 + r;
            if ((i >> 3) == jg) {
                int e = (ti * 2 + jg) * 64 + (i & 7) * 8 + (lc & 7);
                float v = d[r] + lsl[ti * 16 + i] + ldl[arow] + nb;
                pre2[(size_t)rh * cE + e] = v;
                sm += v;
                sq += v * v;
            }
        }
    }
#pragma unroll
    for (int o = 32; o > 0; o >>= 1) {
        sm += __shfl_down(sm, o);
        sq += __shfl_down(sq, o);
    }
    if (l == 0) { rs[w] = sm; rs[4 + w] = sq; }
    __syncthreads();
    if (t == 0) {
        float S = rs[0] + rs[1] + rs[2] + rs[3];
        float Q = rs[4] + rs[5] + rs[6] + rs[7];
        part2[rh] = make_float2(S, Q);
    }
}

// ---------------------------------------------------------------------------
// 7) logit + in-kernel BN2 (single partial per rh) + fused loss partials.
__global__ __launch_bounds__(256) void k_final(
    const float* __restrict__ pre2, const float2* __restrict__ part2,
    const float* __restrict__ g2, const float* __restrict__ b2,
    const float* __restrict__ ntl_u, const int* __restrict__ mask,
    float* __restrict__ out, float* __restrict__ part) {
    int r = blockIdx.y, et = blockIdx.x;
    int t = threadIdx.x;
    __shared__ float sc[32], sh[32];
    if (t < 32) {
        int rh = r * 32 + t;
        float2 pp = part2[rh];
        float mean = pp.x * (1.f / 2048.f);
        float var = pp.y * (1.f / 2048.f) - mean * mean;
        float scv = g2[rh] * rsqrtf(var + cEPS);
        sc[t] = scv;
        sh[t] = b2[rh] - mean * scv;
    }
    __syncthreads();
    int e = et * 256 + t;
    float a = 0.f;
#pragma unroll
    for (int h = 0; h < 32; ++h) {
        int rh = r * 32 + h;
        float p = pre2[(size_t)rh * cE + e];
        a += ntl_u[rh] * ftanh(fmaf(p, sc[h], sh[h]));
    }
    out[(size_t)e * 16 + r] = a;
    int m = mask[(size_t)e * 16 + r];
    bool mb = (m != 0);
    bool eq = ((a > 0.f) == mb);
    float nll = mb ? nls(a) : -logf(1.f / (1.f + expf(a)) + 1e-5f);
    float corr = eq ? 1.f : 0.f;
    unsigned long long bal = __ballot(eq);
    float em = (bal == ~0ull) ? 1.f : 0.f;
#pragma unroll
    for (int o = 32; o > 0; o >>= 1) {
        nll += __shfl_down(nll, o);
        corr += __shfl_down(corr, o);
    }
    if ((t & 63) == 0) {
        int bg = et * 4 + (t >> 6);
        float* p = part + ((size_t)bg * 16 + r) * 4;
        p[0] = nll; p[1] = corr; p[2] = em;
    }
}

// ---------------------------------------------------------------------------
// 8) final loss reduction
__global__ void k_loss_fin(const float* __restrict__ part, float* __restrict__ out) {
    int t = threadIdx.x;
    float nll = 0.f, corr = 0.f, em = 0.f;
    if (t < 32) {
        em = 1.f;
        for (int r = 0; r < 16; ++r) {
            const float* p = part + ((size_t)t * 16 + r) * 4;
            nll += p[0]; corr += p[1]; em = fminf(em, p[2]);
        }
    }
#pragma unroll
    for (int o = 32; o > 0; o >>= 1) {
        nll += __shfl_down(nll, o);
        corr += __shfl_down(corr, o);
        em += __shfl_down(em, o);
    }
    if (t == 0) {
        out[32768] = nll / 32.f;
        out[32769] = corr / 32768.f;
        out[32770] = em / 32.f;
    }
}

}  // namespace

extern "C" void kernel_launch(void* const* d_in, const int* in_sizes, int n_in,
                              void* d_out, int out_size, void* d_ws, size_t ws_size,
                              hipStream_t stream) {
    (void)in_sizes; (void)n_in; (void)out_size; (void)ws_size;
    const int* seq = (const int*)d_in[0];
    const int* p2g = (const int*)d_in[1];
    const int* idx = (const int*)d_in[2];
    const int* mask = (const int*)d_in[5];
    const float* emb = (const float*)d_in[6];
    const float* wih_f = (const float*)d_in[7];
    const float* whh_f = (const float*)d_in[8];
    const float* bih_f = (const float*)d_in[9];
    const float* bhh_f = (const float*)d_in[10];
    const float* wih_b = (const float*)d_in[11];
    const float* whh_b = (const float*)d_in[12];
    const float* bih_b = (const float*)d_in[13];
    const float* bhh_b = (const float*)d_in[14];
    const float* lsw = (const float*)d_in[15];
    const float* lsb = (const float*)d_in[16];
    const float* ldw = (const float*)d_in[17];
    const float* ldb = (const float*)d_in[18];
    const float* bn_sg = (const float*)d_in[19];
    const float* bn_sb = (const float*)d_in[20];
    const float* bn_dg = (const float*)d_in[21];
    const float* bn_db = (const float*)d_in[22];
    const float* ntlw = (const float*)d_in[23];
    const float* ntlv = (const float*)d_in[24];
    const float* ntlb = (const float*)d_in[25];
    const float* ntlu = (const float*)d_in[26];
    const float* bn2g = (const float*)d_in[27];
    const float* bn2b = (const float*)d_in[28];
    float* out = (float*)d_out;
    char* ws = (char*)d_ws;

    float* x_seq = (float*)(ws + 0);
    float* pre = (float*)(ws + 2097152);
    size_t off = 33554432;
    unsigned short* h_out = (unsigned short*)(ws + off); off += 1048576;
    float* hsumT = (float*)(ws + off); off += 262144;
    float* hd_bn = (float*)(ws + off); off += 131072;
    float* tl_bn = (float*)(ws + off); off += 131072;
    unsigned short* tl_bf = (unsigned short*)(ws + off); off += 65536;
    float* pre2 = (float*)(ws + off); off += 4194304;
    float2* part2 = (float2*)(ws + off); off += 4096;
    float* part = (float*)(ws + off); off += 8192;

    k_embed<<<32, 256, 0, stream>>>(seq, p2g, emb, x_seq);
    k_gemm_in<<<dim3(8, 64), 512, 0, stream>>>(x_seq, wih_f, wih_b, bih_f, bhh_f, bih_b, bhh_b, pre);
    k_lstm_m<<<4, 512, 0, stream>>>(pre, whh_f, whh_b, h_out);
    k_gather<<<256, 256, 0, stream>>>(idx, p2g, h_out, hsumT);
    k_proj_bn<<<dim3(2, 128), 256, 0, stream>>>(hsumT, lsw, lsb, ldw, ldb,
                                                bn_sg, bn_sb, bn_dg, bn_db, hd_bn, tl_bn, tl_bf);
    k_ntl<<<512, 256, 0, stream>>>(hd_bn, tl_bn, tl_bf, ntlw, ntlv, ntlb, pre2, part2);
    k_final<<<dim3(8, 16), 256, 0, stream>>>(pre2, part2, bn2g, bn2b, ntlu, mask, out, part);
    k_loss_fin<<<1, 64, 0, stream>>>(part, out);
}

// Round 15
// 154.719 us; speedup vs baseline: 1.7754x; 1.0111x over previous
//
#include <hip/hip_runtime.h>
#include <math.h>

namespace {

constexpr int cB = 32, cL = 128, cG = 64, cD = 256;
constexpr int cHD = 128, cH = 256;
constexpr int cN = 8, cK = 4;
constexpr int cNI = 128, cRH = 512;
constexpr int cE = 2048;
constexpr float cEPS = 1e-5f;

typedef __bf16 bf16x8 __attribute__((ext_vector_type(8)));
typedef float f32x4 __attribute__((ext_vector_type(4)));

__device__ __forceinline__ f32x4 mfma16(bf16x8 a, bf16x8 b, f32x4 c) {
    return __builtin_amdgcn_mfma_f32_16x16x32_bf16(a, b, c, 0, 0, 0);
}

__device__ __forceinline__ float bf2f(unsigned short u) {
    unsigned int x = ((unsigned int)u) << 16;
    return __uint_as_float(x);
}
__device__ __forceinline__ unsigned short f2bf(float f) {
    unsigned int x = __float_as_uint(f);
    unsigned int r = (x + 0x7fffu + ((x >> 16) & 1u)) >> 16;  // RNE
    return (unsigned short)r;
}
__device__ __forceinline__ float frcp(float x) { return __builtin_amdgcn_rcpf(x); }
__device__ __forceinline__ float fsig(float x) { return frcp(1.f + __expf(-x)); }
__device__ __forceinline__ float ftanh(float x) { return 1.f - 2.f * frcp(__expf(2.f * x) + 1.f); }
__device__ __forceinline__ float nls(float x) {
    return (x >= 0.f) ? log1pf(expf(-x)) : (log1pf(expf(x)) - x);
}
__device__ __forceinline__ bf16x8 cvt8(const float* __restrict__ p) {
    float4 a = *(const float4*)p, b = *(const float4*)(p + 4);
    bf16x8 v;
    v[0] = (__bf16)a.x; v[1] = (__bf16)a.y; v[2] = (__bf16)a.z; v[3] = (__bf16)a.w;
    v[4] = (__bf16)b.x; v[5] = (__bf16)b.y; v[6] = (__bf16)b.z; v[7] = (__bf16)b.w;
    return v;
}

// lgkm-only barrier: LDS ping-pong needs lgkmcnt ordering, NOT a vmcnt(0) drain.
__device__ __forceinline__ void bar_lgkm() {
    asm volatile("s_waitcnt lgkmcnt(0)\n\ts_barrier" ::: "memory");
}

// ---------------------------------------------------------------------------
// 1) token embedding + scatter_sum (verified).
__global__ __launch_bounds__(256) void k_embed(
    const int* __restrict__ seq, const int* __restrict__ p2g,
    const float* __restrict__ emb, float* __restrict__ x_seq) {
    __shared__ float xl[cG * cD];
    __shared__ int toks[cL], grps[cL];
    int b = blockIdx.x, t = threadIdx.x;
    if (t < 128) toks[t] = seq[b * cL + t];
    else grps[t - 128] = p2g[b * cL + (t - 128)];
    for (int g = 0; g < cG; ++g) xl[g * cD + t] = 0.f;
    __syncthreads();
    for (int l = 0; l < cL; l += 4) {
        float v0 = emb[(size_t)toks[l + 0] * cD + t];
        float v1 = emb[(size_t)toks[l + 1] * cD + t];
        float v2 = emb[(size_t)toks[l + 2] * cD + t];
        float v3 = emb[(size_t)toks[l + 3] * cD + t];
        xl[grps[l + 0] * cD + t] += v0;
        xl[grps[l + 1] * cD + t] += v1;
        xl[grps[l + 2] * cD + t] += v2;
        xl[grps[l + 3] * cD + t] += v3;
    }
    for (int g = 0; g < cG; ++g)
        x_seq[(g * cB + b) * cD + t] = xl[g * cD + t];
}

// ---------------------------------------------------------------------------
// 2) LSTM input GEMM via MFMA (verified).
__global__ __launch_bounds__(512) void k_gemm_in(
    const float* __restrict__ x_seq,
    const float* __restrict__ wih_f, const float* __restrict__ wih_b,
    const float* __restrict__ bih_f, const float* __restrict__ bhh_f,
    const float* __restrict__ bih_b, const float* __restrict__ bhh_b,
    float* __restrict__ pre) {
    int ns = blockIdx.x, g = blockIdx.y;
    int t = threadIdx.x;
    int w = t >> 6, l = t & 63, lc = l & 15, lk = l >> 4;
    int gn = ns * 128 + w * 16 + lc;
    const float* wrow = (gn < 512) ? (wih_f + (size_t)gn * cD)
                                   : (wih_b + (size_t)(gn - 512) * cD);
    const float* xb0 = x_seq + ((size_t)g * 32 + lc) * cD;
    const float* xb1 = x_seq + ((size_t)g * 32 + 16 + lc) * cD;
    f32x4 acc0 = {0.f, 0.f, 0.f, 0.f}, acc1 = {0.f, 0.f, 0.f, 0.f};
#pragma unroll
    for (int kf = 0; kf < 8; ++kf) {
        int ko = kf * 32 + lk * 8;
        bf16x8 a = cvt8(wrow + ko);
        bf16x8 b0 = cvt8(xb0 + ko);
        bf16x8 b1 = cvt8(xb1 + ko);
        acc0 = mfma16(a, b0, acc0);
        acc1 = mfma16(a, b1, acc1);
    }
    int nb = ns * 128 + w * 16 + lk * 4;
    float4 bv;
    if (nb < 512) {
        float4 u = *(const float4*)(bih_f + nb);
        float4 v = *(const float4*)(bhh_f + nb);
        bv = make_float4(u.x + v.x, u.y + v.y, u.z + v.z, u.w + v.w);
    } else {
        float4 u = *(const float4*)(bih_b + nb - 512);
        float4 v = *(const float4*)(bhh_b + nb - 512);
        bv = make_float4(u.x + v.x, u.y + v.y, u.z + v.z, u.w + v.w);
    }
    size_t base = ((size_t)g * 256 + (nb >> 2)) * 32;
    *(float4*)(pre + (base + lc) * 4) =
        make_float4(acc0[0] + bv.x, acc0[1] + bv.y, acc0[2] + bv.z, acc0[3] + bv.w);
    *(float4*)(pre + (base + 16 + lc) * 4) =
        make_float4(acc1[0] + bv.x, acc1[1] + bv.y, acc1[2] + bv.z, acc1[3] + bv.w);
}

// ---------------------------------------------------------------------------
// 3) MFMA LSTM — round-8 proven config (59.6us, VGPR 76, no spill).
__device__ __forceinline__ void lstm_step(
    f32x4 (&acc)[4], float (&cst)[4], const bf16x8 (&wf)[4][4],
    const unsigned short* __restrict__ hr, unsigned short* __restrict__ hw,
    const int (&rdo)[4], int wro,
    const float* __restrict__ preb, int gpre, bool dopre,
    unsigned short* __restrict__ hob, int g) {
    bf16x8 hf[4];
#pragma unroll
    for (int kf = 0; kf < 4; ++kf)
        hf[kf] = *(const bf16x8*)((const char*)hr + rdo[kf]);
#pragma unroll
    for (int kf = 0; kf < 4; ++kf)
#pragma unroll
        for (int q = 0; q < 4; ++q)
            acc[q] = mfma16(wf[q][kf], hf[kf], acc[q]);
    float hv[4];
#pragma unroll
    for (int r = 0; r < 4; ++r) {
        float ig = fsig(acc[0][r]);
        float fg = fsig(acc[1][r]);
        float gg = ftanh(acc[2][r]);
        float og = fsig(acc[3][r]);
        float cv = fg * cst[r] + ig * gg;
        cst[r] = cv;
        hv[r] = og * ftanh(cv);
    }
    if (dopre) {
#pragma unroll
        for (int q = 0; q < 4; ++q)
            acc[q] = *(const f32x4*)(preb + (size_t)gpre * 32768 + q * 4096);
    }
    unsigned int p0 = (unsigned int)f2bf(hv[0]) | ((unsigned int)f2bf(hv[1]) << 16);
    unsigned int p1 = (unsigned int)f2bf(hv[2]) | ((unsigned int)f2bf(hv[3]) << 16);
    *(uint2*)((char*)hw + wro) = make_uint2(p0, p1);
    *(uint2*)(hob + (size_t)g * 8192) = make_uint2(p0, p1);
    bar_lgkm();
}

__global__ __launch_bounds__(512, 2) void k_lstm_m(
    const float* __restrict__ pre,
    const float* __restrict__ whh_f, const float* __restrict__ whh_b,
    unsigned short* __restrict__ h_out) {
    __shared__ __align__(16) unsigned short hl[2][2048];
    int t = threadIdx.x;
    int w = t >> 6, l = t & 63, lc = l & 15, lk = l >> 4;
    int dir = blockIdx.x >> 1, bg = (blockIdx.x & 1) * 16;
    const float* whh = dir ? whh_b : whh_f;
    bf16x8 wf[4][4];
#pragma unroll
    for (int q = 0; q < 4; ++q) {
        int n = q * 128 + w * 16 + lc;
#pragma unroll
        for (int kf = 0; kf < 4; ++kf)
            wf[q][kf] = cvt8(whh + (size_t)n * 128 + kf * 32 + lk * 8);
    }
    *(uint2*)&hl[1][t * 4] = make_uint2(0u, 0u);
    const float* preb = pre + ((size_t)(dir * 128 + w * 4 + lk) * 32 + (bg + lc)) * 4;
    unsigned short* hob = h_out + ((size_t)(dir * 32 + bg + lc) * 128 + w * 16 + lk * 4);
    int rdo[4];
#pragma unroll
    for (int kf = 0; kf < 4; ++kf)
        rdo[kf] = (lc * 256 + kf * 64 + lk * 16) ^ (lc << 4);
    int wro = (lc * 256 + w * 32 + lk * 8) ^ (lc << 4);
    f32x4 accA[4], accB[4];
    float cst[4] = {0.f, 0.f, 0.f, 0.f};
    int g0 = dir ? 63 : 0;
    int sgn = dir ? -1 : 1;
#pragma unroll
    for (int q = 0; q < 4; ++q) accA[q] = *(const f32x4*)(preb + (size_t)g0 * 32768 + q * 4096);
#pragma unroll
    for (int q = 0; q < 4; ++q) accB[q] = *(const f32x4*)(preb + (size_t)(g0 + sgn) * 32768 + q * 4096);
    bar_lgkm();
    for (int s = 0; s < 64; s += 2) {
        int ga = g0 + sgn * s;
        lstm_step(accA, cst, wf, hl[1], hl[0], rdo, wro, preb, ga + 2 * sgn, s < 62, hob, ga);
        lstm_step(accB, cst, wf, hl[0], hl[1], rdo, wro, preb, ga + 3 * sgn, s < 61, hob, ga + sgn);
    }
}

// ---------------------------------------------------------------------------
// 4) gather(+sum over K) -> transposed hsumT[c][n] (verified).
__global__ __launch_bounds__(256) void k_gather(
    const int* __restrict__ idx, const int* __restrict__ p2g,
    const unsigned short* __restrict__ h_out, float* __restrict__ hsumT) {
    int bn = blockIdx.x;
    int b = bn >> 3;
    int t = threadIdx.x;
    int dirq = t >> 7, hh = t & 127;
    int l0 = idx[bn * cK + 0], l1 = idx[bn * cK + 1];
    int l2 = idx[bn * cK + 2], l3 = idx[bn * cK + 3];
    int g0 = p2g[b * cL + l0], g1 = p2g[b * cL + l1];
    int g2 = p2g[b * cL + l2], g3 = p2g[b * cL + l3];
    size_t ro = (size_t)(dirq * 32 + b) * 128 + hh;
    float a = bf2f(h_out[(size_t)g0 * 8192 + ro]) + bf2f(h_out[(size_t)g1 * 8192 + ro]) +
              bf2f(h_out[(size_t)g2 * 8192 + ro]) + bf2f(h_out[(size_t)g3 * 8192 + ro]);
    hsumT[(size_t)t * 256 + bn] = a;
}

// ---------------------------------------------------------------------------
// 5) fused projection + BatchNorm; dst side also emits bf16 copy (verified).
__global__ __launch_bounds__(256) void k_proj_bn(
    const float* __restrict__ hsumT,
    const float* __restrict__ w_src, const float* __restrict__ b_src,
    const float* __restrict__ w_dst, const float* __restrict__ b_dst,
    const float* __restrict__ g_src, const float* __restrict__ bb_src,
    const float* __restrict__ g_dst, const float* __restrict__ bb_dst,
    float* __restrict__ hd_bn, float* __restrict__ tl_bn,
    unsigned short* __restrict__ tl_bf) {
    int which = blockIdx.x, c = blockIdx.y, t = threadIdx.x;
    __shared__ float ws[256];
    __shared__ float ssum[256], ssq[256];
    ws[t] = (which ? w_dst : w_src)[(size_t)c * cH + t];
    __syncthreads();
    float acc = (which ? b_dst : b_src)[c];
#pragma unroll 8
    for (int k = 0; k < cH; ++k)
        acc += ws[k] * hsumT[(size_t)k * 256 + t];
    ssum[t] = acc;
    ssq[t] = acc * acc;
    __syncthreads();
    for (int o = 128; o > 0; o >>= 1) {
        if (t < o) { ssum[t] += ssum[t + o]; ssq[t] += ssq[t + o]; }
        __syncthreads();
    }
    float mean = ssum[0] * (1.f / 256.f);
    float var = ssq[0] * (1.f / 256.f) - mean * mean;
    float gam = which ? g_dst[c] : g_src[c];
    float bet = which ? bb_dst[c] : bb_src[c];
    float scale = gam * rsqrtf(var + cEPS);
    float val = (acc - mean) * scale + bet;
    (which ? tl_bn : hd_bn)[(size_t)t * cNI + c] = val;
    if (which) tl_bf[(size_t)t * cNI + c] = f2bf(val);
}

// ---------------------------------------------------------------------------
// 6) FUSED NTL (+BN2+tanh+u): per-rh block computes lin, T = hd@W, T->LDS,
//    P = T.tl^T diagonal tiles, in-block BN stats + scale/shift broadcast,
//    act[rh][e] = u[rh]*tanh(BN(P)) stored bf16. No pre2 / part2 buffers.
__global__ __launch_bounds__(256, 2) void k_ntl(
    const float* __restrict__ hd_bn, const float* __restrict__ tl_bn,
    const unsigned short* __restrict__ tl_bf,
    const float* __restrict__ ntl_w, const float* __restrict__ ntl_v,
    const float* __restrict__ ntl_b, const float* __restrict__ ntl_u,
    const float* __restrict__ g2, const float* __restrict__ b2,
    unsigned short* __restrict__ act) {
    __shared__ __align__(16) unsigned short Tl[256 * 128];  // 64KB; first 32KB = W stage
    __shared__ float vsh[256];
    __shared__ float lsl[256], ldl[256];
    __shared__ float rs[8];
    int rh = blockIdx.x, t = threadIdx.x;
    int w = t >> 6, l = t & 63, lc = l & 15, lk = l >> 4;
    vsh[t] = ntl_v[(size_t)rh * 256 + t];
    unsigned short* wl = Tl;
    {
        const float* wbase = ntl_w + (size_t)rh * 16384;
        int k = t >> 1, c0 = (t & 1) * 64;
        int sw = ((k >> 3) & 3) << 4;
#pragma unroll
        for (int u = 0; u < 8; ++u) {
            bf16x8 v = cvt8(wbase + k * 128 + c0 + u * 8);
            *(bf16x8*)((char*)wl + ((k * 256 + (c0 + u * 8) * 2) ^ sw)) = v;
        }
    }
    __syncthreads();
    // lin part -> LDS only
    {
        const float* hr = hd_bn + (size_t)t * cNI;
        const float* tr = tl_bn + (size_t)t * cNI;
        float a1 = 0.f, a2 = 0.f;
#pragma unroll 8
        for (int i = 0; i < cNI; i += 4) {
            float4 h4 = *(const float4*)(hr + i);
            float4 t4 = *(const float4*)(tr + i);
            a1 += h4.x * vsh[i] + h4.y * vsh[i + 1] + h4.z * vsh[i + 2] + h4.w * vsh[i + 3];
            a2 += t4.x * vsh[128 + i] + t4.y * vsh[128 + i + 1] + t4.z * vsh[128 + i + 2] + t4.w * vsh[128 + i + 3];
        }
        lsl[t] = a1;
        ldl[t] = a2;
    }
    // phase 1: T = hd @ W
    f32x4 acc[4][8] = {};
#pragma unroll
    for (int kf = 0; kf < 4; ++kf) {
        bf16x8 af[4];
#pragma unroll
        for (int mt = 0; mt < 4; ++mt) {
            int m = w * 64 + mt * 16 + lc;
            af[mt] = cvt8(hd_bn + (size_t)m * 128 + kf * 32 + lk * 8);
        }
#pragma unroll
        for (int nt = 0; nt < 8; ++nt) {
            int kb = (kf * 32 + lk * 8) * 256;
            int jb = (nt * 16 + lc) * 2;
            bf16x8 bv = *(const bf16x8*)((char*)wl + ((kb + jb) ^ (lk << 4)));
#pragma unroll
            for (int mt = 0; mt < 4; ++mt) acc[mt][nt] = mfma16(af[mt], bv, acc[mt][nt]);
        }
    }
    __syncthreads();  // all W reads done; safe to overwrite with T
#pragma unroll
    for (int mt = 0; mt < 4; ++mt) {
#pragma unroll
        for (int nt = 0; nt < 8; ++nt) {
#pragma unroll
            for (int r = 0; r < 4; ++r) {
                int row = w * 64 + mt * 16 + lk * 4 + r;
                int col = nt * 16 + lc;
                int byte = (row * 256 + col * 2) ^ ((row & 7) << 4);
                *(unsigned short*)((char*)Tl + byte) = f2bf(acc[mt][nt][r]);
            }
        }
    }
    __syncthreads();
    // phase 2: diagonal 16x16 tiles; keep-condition is lane-uniform:
    // (i>>3)==jg  <=>  (lk>=2)==(lc>=8)
    float nb = ntl_b[rh];
    float sm = 0.f, sq = 0.f;
    float vals[4][4];
    int jg = lc >> 3;
#pragma unroll
    for (int p = 0; p < 4; ++p) {
        int ti = w * 4 + p;
        int arow = ti * 16 + lc;
        f32x4 d = {0.f, 0.f, 0.f, 0.f};
#pragma unroll
        for (int kf = 0; kf < 4; ++kf) {
            const char* ta = (const char*)Tl +
                ((arow * 256 + (kf * 32 + lk * 8) * 2) ^ ((arow & 7) << 4));
            bf16x8 a = *(const bf16x8*)ta;
            bf16x8 b = *(const bf16x8*)(tl_bf + (size_t)arow * 128 + kf * 32 + lk * 8);
            d = mfma16(a, b, d);
        }
#pragma unroll
        for (int r = 0; r < 4; ++r) {
            int i = lk * 4 + r;
            float v = d[r] + lsl[ti * 16 + i] + ldl[arow] + nb;
            vals[p][r] = v;
            if ((i >> 3) == jg) { sm += v; sq += v * v; }
        }
    }
#pragma unroll
    for (int o = 32; o > 0; o >>= 1) {
        sm += __shfl_down(sm, o);
        sq += __shfl_down(sq, o);
    }
    if (l == 0) { rs[w] = sm; rs[4 + w] = sq; }
    __syncthreads();
    float S = rs[0] + rs[1] + rs[2] + rs[3];
    float Q = rs[4] + rs[5] + rs[6] + rs[7];
    float mean = S * (1.f / 2048.f);
    float var = Q * (1.f / 2048.f) - mean * mean;
    float scv = g2[rh] * rsqrtf(var + cEPS);
    float shv = b2[rh] - mean * scv;
    float uu = ntl_u[rh];
    unsigned short* arow_base = act + (size_t)rh * cE;
#pragma unroll
    for (int p = 0; p < 4; ++p) {
        int ti = w * 4 + p;
#pragma unroll
        for (int r = 0; r < 4; ++r) {
            int i = lk * 4 + r;
            if ((i >> 3) == jg) {
                int e = (ti * 2 + jg) * 64 + (i & 7) * 8 + (lc & 7);
                arow_base[e] = f2bf(uu * ftanh(fmaf(vals[p][r], scv, shv)));
            }
        }
    }
}

// ---------------------------------------------------------------------------
// 7) logit = sum of 32 bf16 act terms + fused loss partials (pure bandwidth).
__global__ __launch_bounds__(256) void k_final(
    const unsigned short* __restrict__ act, const int* __restrict__ mask,
    float* __restrict__ out, float* __restrict__ part) {
    int r = blockIdx.y, et = blockIdx.x;
    int t = threadIdx.x;
    int e = et * 256 + t;
    float a = 0.f;
#pragma unroll
    for (int h = 0; h < 32; ++h)
        a += bf2f(act[(size_t)(r * 32 + h) * cE + e]);
    out[(size_t)e * 16 + r] = a;
    int m = mask[(size_t)e * 16 + r];
    bool mb = (m != 0);
    bool eq = ((a > 0.f) == mb);
    float nll = mb ? nls(a) : -logf(1.f / (1.f + expf(a)) + 1e-5f);
    float corr = eq ? 1.f : 0.f;
    unsigned long long bal = __ballot(eq);
    float em = (bal == ~0ull) ? 1.f : 0.f;
#pragma unroll
    for (int o = 32; o > 0; o >>= 1) {
        nll += __shfl_down(nll, o);
        corr += __shfl_down(corr, o);
    }
    if ((t & 63) == 0) {
        int bg = et * 4 + (t >> 6);
        float* p = part + ((size_t)bg * 16 + r) * 4;
        p[0] = nll; p[1] = corr; p[2] = em;
    }
}

// ---------------------------------------------------------------------------
// 8) final loss reduction
__global__ void k_loss_fin(const float* __restrict__ part, float* __restrict__ out) {
    int t = threadIdx.x;
    float nll = 0.f, corr = 0.f, em = 0.f;
    if (t < 32) {
        em = 1.f;
        for (int r = 0; r < 16; ++r) {
            const float* p = part + ((size_t)t * 16 + r) * 4;
            nll += p[0]; corr += p[1]; em = fminf(em, p[2]);
        }
    }
#pragma unroll
    for (int o = 32; o > 0; o >>= 1) {
        nll += __shfl_down(nll, o);
        corr += __shfl_down(corr, o);
        em += __shfl_down(em, o);
    }
    if (t == 0) {
        out[32768] = nll / 32.f;
        out[32769] = corr / 32768.f;
        out[32770] = em / 32.f;
    }
}

}  // namespace

extern "C" void kernel_launch(void* const* d_in, const int* in_sizes, int n_in,
                              void* d_out, int out_size, void* d_ws, size_t ws_size,
                              hipStream_t stream) {
    (void)in_sizes; (void)n_in; (void)out_size; (void)ws_size;
    const int* seq = (const int*)d_in[0];
    const int* p2g = (const int*)d_in[1];
    const int* idx = (const int*)d_in[2];
    const int* mask = (const int*)d_in[5];
    const float* emb = (const float*)d_in[6];
    const float* wih_f = (const float*)d_in[7];
    const float* whh_f = (const float*)d_in[8];
    const float* bih_f = (const float*)d_in[9];
    const float* bhh_f = (const float*)d_in[10];
    const float* wih_b = (const float*)d_in[11];
    const float* whh_b = (const float*)d_in[12];
    const float* bih_b = (const float*)d_in[13];
    const float* bhh_b = (const float*)d_in[14];
    const float* lsw = (const float*)d_in[15];
    const float* lsb = (const float*)d_in[16];
    const float* ldw = (const float*)d_in[17];
    const float* ldb = (const float*)d_in[18];
    const float* bn_sg = (const float*)d_in[19];
    const float* bn_sb = (const float*)d_in[20];
    const float* bn_dg = (const float*)d_in[21];
    const float* bn_db = (const float*)d_in[22];
    const float* ntlw = (const float*)d_in[23];
    const float* ntlv = (const float*)d_in[24];
    const float* ntlb = (const float*)d_in[25];
    const float* ntlu = (const float*)d_in[26];
    const float* bn2g = (const float*)d_in[27];
    const float* bn2b = (const float*)d_in[28];
    float* out = (float*)d_out;
    char* ws = (char*)d_ws;

    float* x_seq = (float*)(ws + 0);
    float* pre = (float*)(ws + 2097152);
    size_t off = 33554432;
    unsigned short* h_out = (unsigned short*)(ws + off); off += 1048576;
    float* hsumT = (float*)(ws + off); off += 262144;
    float* hd_bn = (float*)(ws + off); off += 131072;
    float* tl_bn = (float*)(ws + off); off += 131072;
    unsigned short* tl_bf = (unsigned short*)(ws + off); off += 65536;
    unsigned short* act = (unsigned short*)(ws + off); off += 2097152;
    float* part = (float*)(ws + off); off += 8192;

    k_embed<<<32, 256, 0, stream>>>(seq, p2g, emb, x_seq);
    k_gemm_in<<<dim3(8, 64), 512, 0, stream>>>(x_seq, wih_f, wih_b, bih_f, bhh_f, bih_b, bhh_b, pre);
    k_lstm_m<<<4, 512, 0, stream>>>(pre, whh_f, whh_b, h_out);
    k_gather<<<256, 256, 0, stream>>>(idx, p2g, h_out, hsumT);
    k_proj_bn<<<dim3(2, 128), 256, 0, stream>>>(hsumT, lsw, lsb, ldw, ldb,
                                                bn_sg, bn_sb, bn_dg, bn_db, hd_bn, tl_bn, tl_bf);
    k_ntl<<<512, 256, 0, stream>>>(hd_bn, tl_bn, tl_bf, ntlw, ntlv, ntlb, ntlu, bn2g, bn2b, act);
    k_final<<<dim3(8, 16), 256, 0, stream>>>(act, mask, out, part);
    k_loss_fin<<<1, 64, 0, stream>>>(part, out);
}